// Round 1
// baseline (9232.529 us; speedup 1.0000x reference)
//
#include <hip/hip_runtime.h>
#include <math.h>

#define HH 192
#define WW 192
#define WF 97
#define NC 8
#define NC2 16
#define NT 32
#define NB 2
#define NIMG (NB*NT)        // 64
#define NPLANE (NIMG*NC)    // 512
#define PIX (HH*WW)         // 36864
#define FPIX (HH*WF)        // 18624
#define CHUNK 16            // images per conv chunk
#define INV_SQRT_N 0.07216878364870322f   // 1/sqrt(192)

// ---------------- tables + norm zero ----------------
__global__ void k_tab(float* tw, float* nrm){
    int i = blockIdx.x*blockDim.x + threadIdx.x;
    if (i < 192){
        double ang = 6.283185307179586476925286766559 * (double)i / 192.0;
        tw[i]       = (float)cos(ang);
        tw[192 + i] = (float)sin(ang);
    }
    if (i < 128) nrm[i] = 0.0f;
}

// ---------------- A = exp(i*omega*dt) via MLP ----------------
__global__ void k_A(const float* __restrict__ dt, const float* __restrict__ w1,
                    const float* __restrict__ b1, const float* __restrict__ w2,
                    const float* __restrict__ b2, float* __restrict__ Abuf){
    int idx = blockIdx.x*blockDim.x + threadIdx.x;
    if (idx >= FPIX) return;
    int i = idx / WF, j = idx % WF;
    float ky = (float)(i < 96 ? i : i - 192) / 192.0f;
    float kx = (float)j / 192.0f;
    float lp[NC];
    #pragma unroll
    for (int c = 0; c < NC; c++) lp[c] = b2[c];
    for (int jh = 0; jh < 64; jh++){
        float z  = ky*w1[jh] + kx*w1[64+jh] + b1[jh];
        float sg = 1.0f/(1.0f + expf(-z));
        float h  = z*sg;
        #pragma unroll
        for (int c = 0; c < NC; c++) lp[c] += h * w2[jh*NC + c];
    }
    float kph = sqrtf(ky*ky + kx*kx);
    for (int b = 0; b < NB; b++){
        float d = dt[b];
        #pragma unroll
        for (int c = 0; c < NC; c++){
            float ph = (lp[c] + kph) * d;
            float s, cn;
            sincosf(ph, &s, &cn);
            long o = (((long)(b*NC + c))*FPIX + idx) * 2;
            Abuf[o]   = cn;
            Abuf[o+1] = s;
        }
    }
}

// ---------------- conv1 forward: ys1=silu(y1), dy1=silu'(y1) ----------------
__global__ void k_conv1(const float* __restrict__ x, const float* __restrict__ c1w,
                        const float* __restrict__ c1b, float* __restrict__ ys1,
                        float* __restrict__ dy1, int img0){
    int idx = blockIdx.x*256 + threadIdx.x;            // CHUNK*NC2*PIX exact
    int j = idx % WW; int tmp = idx / WW;
    int i = tmp % HH; tmp /= HH;
    int o = tmp % NC2; int il = tmp / NC2;
    const float* xb = x + ((long)(img0 + il))*NC*PIX;
    float acc = c1b[o];
    for (int c = 0; c < NC; c++){
        const float* xc = xb + c*PIX;
        #pragma unroll
        for (int dy = 0; dy < 3; dy++){
            int yy = i + dy - 1; if (yy < 0 || yy >= HH) continue;
            #pragma unroll
            for (int dx = 0; dx < 3; dx++){
                int xx = j + dx - 1; if (xx < 0 || xx >= WW) continue;
                acc += c1w[((o*NC + c)*3 + dy)*3 + dx] * xc[yy*WW + xx];
            }
        }
    }
    float sg = 1.0f/(1.0f + expf(-acc));
    ys1[idx] = acc*sg;
    dy1[idx] = sg*(1.0f + acc*(1.0f - sg));
}

// ---------------- conv2 forward + g2 = silu'(y2) * s3 ----------------
__global__ void k_conv2g2(const float* __restrict__ ys1, const float* __restrict__ c2w,
                          const float* __restrict__ c2b, const float* __restrict__ c3w,
                          float* __restrict__ g2){
    int idx = blockIdx.x*256 + threadIdx.x;
    int j = idx % WW; int tmp = idx / WW;
    int i = tmp % HH; tmp /= HH;
    int c2o = tmp % NC2; int il = tmp / NC2;
    const float* yb = ys1 + (long)il*NC2*PIX;
    float acc = c2b[c2o];
    for (int c1 = 0; c1 < NC2; c1++){
        const float* yc = yb + c1*PIX;
        #pragma unroll
        for (int dy = 0; dy < 3; dy++){
            int yy = i + dy - 1; if (yy < 0 || yy >= HH) continue;
            #pragma unroll
            for (int dx = 0; dx < 3; dx++){
                int xx = j + dx - 1; if (xx < 0 || xx >= WW) continue;
                acc += c2w[((c2o*NC2 + c1)*3 + dy)*3 + dx] * yc[yy*WW + xx];
            }
        }
    }
    float sg = 1.0f/(1.0f + expf(-acc));
    float ds = sg*(1.0f + acc*(1.0f - sg));
    float s3 = 0.0f;
    #pragma unroll
    for (int o = 0; o < NC; o++) s3 += c3w[o*NC2 + c2o];
    g2[idx] = ds * s3;
}

// ---------------- g1 = dy1 * conv2^T(g2) ----------------
__global__ void k_g1(const float* __restrict__ g2, const float* __restrict__ dy1,
                     const float* __restrict__ c2w, float* __restrict__ g1){
    int idx = blockIdx.x*256 + threadIdx.x;
    int j = idx % WW; int tmp = idx / WW;
    int i = tmp % HH; tmp /= HH;
    int c1 = tmp % NC2; int il = tmp / NC2;
    float acc = 0.0f;
    for (int c2 = 0; c2 < NC2; c2++){
        const float* gc = g2 + ((long)il*NC2 + c2)*PIX;
        #pragma unroll
        for (int dy = 0; dy < 3; dy++){
            int yy = i + 1 - dy; if (yy < 0 || yy >= HH) continue;
            #pragma unroll
            for (int dx = 0; dx < 3; dx++){
                int xx = j + 1 - dx; if (xx < 0 || xx >= WW) continue;
                acc += c2w[((c2*NC2 + c1)*3 + dy)*3 + dx] * gc[yy*WW + xx];
            }
        }
    }
    g1[idx] = acc * dy1[idx];
}

// ---------------- xp = x + dt * conv1^T(g1)  -> d_out ----------------
__global__ void k_xp(const float* __restrict__ x, const float* __restrict__ g1,
                     const float* __restrict__ c1w, const float* __restrict__ dt,
                     float* __restrict__ xp, int img0){
    int idx = blockIdx.x*256 + threadIdx.x;            // CHUNK*NC*PIX exact
    int j = idx % WW; int tmp = idx / WW;
    int i = tmp % HH; tmp /= HH;
    int c = tmp % NC; int il = tmp / NC;
    int img = img0 + il;
    int b = img / NT;
    float acc = 0.0f;
    for (int o = 0; o < NC2; o++){
        const float* gc = g1 + ((long)il*NC2 + o)*PIX;
        #pragma unroll
        for (int dy = 0; dy < 3; dy++){
            int yy = i + 1 - dy; if (yy < 0 || yy >= HH) continue;
            #pragma unroll
            for (int dx = 0; dx < 3; dx++){
                int xx = j + 1 - dx; if (xx < 0 || xx >= WW) continue;
                acc += c1w[((o*NC + c)*3 + dy)*3 + dx] * gc[yy*WW + xx];
            }
        }
    }
    long gi = (((long)img*NC + c)*PIX) + i*WW + j;
    xp[gi] = x[gi] + dt[b]*acc;
}

// ---------------- forward row rfft: real 192 -> complex 97 ----------------
__global__ void k_rowfft(const float* __restrict__ xp, const float* __restrict__ tw,
                         float* __restrict__ R){
    __shared__ float row[WW], tc[192], ts[192];
    long blk = blockIdx.x;                        // plane*HH + y
    const float* src = xp + blk*WW;
    for (int t = threadIdx.x; t < 192; t += blockDim.x){
        row[t] = src[t]; tc[t] = tw[t]; ts[t] = tw[192+t];
    }
    __syncthreads();
    int k = threadIdx.x;
    if (k < WF){
        float re = 0.0f, im = 0.0f; int m = 0;
        for (int x2 = 0; x2 < WW; x2++){
            float v = row[x2];
            re += v*tc[m]; im -= v*ts[m];
            m += k; if (m >= 192) m -= 192;
        }
        float* dst = R + (blk*WF + k)*2;
        dst[0] = re*INV_SQRT_N; dst[1] = im*INV_SQRT_N;
    }
}

// ---------------- forward col fft: complex 192 -> complex 192 (e^{-i}) ------
__global__ void k_colfft(const float* __restrict__ R, const float* __restrict__ tw,
                         float* __restrict__ Xf){
    __shared__ float cr[HH], ci[HH], tc[192], ts[192];
    int p = blockIdx.x / WF, k = blockIdx.x % WF;
    int t = threadIdx.x;                          // 192
    long e = (((long)p*HH + t)*WF + k)*2;
    cr[t] = R[e]; ci[t] = R[e+1];
    tc[t] = tw[t]; ts[t] = tw[192+t];
    __syncthreads();
    int ky = t;
    float re = 0.0f, im = 0.0f; int m = 0;
    for (int y = 0; y < HH; y++){
        float c_ = tc[m], s_ = ts[m];
        re += cr[y]*c_ + ci[y]*s_;
        im += ci[y]*c_ - cr[y]*s_;
        m += ky; if (m >= 192) m -= 192;
    }
    long o = (((long)p*HH + ky)*WF + k)*2;
    Xf[o] = re*INV_SQRT_N; Xf[o+1] = im*INV_SQRT_N;
}

// ---------------- divergence projection (channels 0,1) ----------------
__global__ void k_constrain(float* __restrict__ F){
    int idx = blockIdx.x*256 + threadIdx.x;       // NIMG*FPIX exact
    int j = idx % WF; int tmp = idx / WF;
    int i = tmp % HH; int bt = tmp / HH;
    float ky = (float)(i < 96 ? i : i - 192)/192.0f;
    float kx = (float)j/192.0f;
    float k2 = ky*ky + kx*kx;
    if (i == 0 && j == 0) k2 = 1.0f;
    long ui = ((((long)bt*NC + 0)*HH + i)*WF + j)*2;
    long vi = ((((long)bt*NC + 1)*HH + i)*WF + j)*2;
    float ur = F[ui], um = F[ui+1], vr = F[vi], vm = F[vi+1];
    float dr = (ky*ur + kx*vr)/k2;
    float di = (ky*um + kx*vm)/k2;
    F[ui]   = ur - ky*dr;  F[ui+1] = um - ky*di;
    F[vi]   = vr - kx*dr;  F[vi+1] = vm - kx*di;
}

// ---------------- per-(b,t) energy reduction ----------------
__global__ void k_norm(const float* __restrict__ F, float* __restrict__ dst){
    int bt = blockIdx.y;
    __shared__ float red[256];
    float s = 0.0f;
    const float* base = F + (long)bt*NC*FPIX*2;
    for (int e = blockIdx.x*256 + threadIdx.x; e < NC*FPIX; e += gridDim.x*256){
        float re = base[(long)e*2], im = base[(long)e*2 + 1];
        s += re*re + im*im;
    }
    red[threadIdx.x] = s; __syncthreads();
    for (int st = 128; st > 0; st >>= 1){
        if (threadIdx.x < st) red[threadIdx.x] += red[threadIdx.x + st];
        __syncthreads();
    }
    if (threadIdx.x == 0) atomicAdd(&dst[bt], red[0]);
}

// ---------------- time recurrence h[t] = A*h[t-1] + X[t] ----------------
__global__ void k_scan(const float* __restrict__ Xf, const float* __restrict__ Abuf,
                       float* __restrict__ Hf){
    int idx = blockIdx.x*256 + threadIdx.x;       // NB*NC*FPIX exact
    int f = idx % FPIX; int tmp = idx / FPIX;
    int c = tmp % NC; int b = tmp / NC;
    long ao = (((long)(b*NC + c))*FPIX + f)*2;
    float ar = Abuf[ao], ai = Abuf[ao+1];
    float hr = 0.0f, hi = 0.0f;
    for (int t = 0; t < NT; t++){
        long e = (((((long)b*NT + t)*NC + c)*FPIX) + f)*2;
        float xr = Xf[e], xi = Xf[e+1];
        float nr = ar*hr - ai*hi + xr;
        float ni = ar*hi + ai*hr + xi;
        hr = nr; hi = ni;
        Hf[e] = hr; Hf[e+1] = hi;
    }
}

// ---------------- inverse col ifft (e^{+i}) with energy rescale ------------
__global__ void k_invcol(const float* __restrict__ Hf, const float* __restrict__ tw,
                         const float* __restrict__ nrm, float* __restrict__ G){
    __shared__ float cr[HH], ci[HH], tc[192], ts[192];
    int p = blockIdx.x / WF, k = blockIdx.x % WF;
    int bt = p / NC;
    float scale = sqrtf(nrm[bt]) / (sqrtf(nrm[64 + bt]) + 1e-6f);
    int t = threadIdx.x;                          // 192
    long e = (((long)p*HH + t)*WF + k)*2;
    cr[t] = Hf[e]*scale; ci[t] = Hf[e+1]*scale;
    tc[t] = tw[t]; ts[t] = tw[192+t];
    __syncthreads();
    int y = t;
    float re = 0.0f, im = 0.0f; int m = 0;
    for (int q = 0; q < HH; q++){
        float c_ = tc[m], s_ = ts[m];
        re += cr[q]*c_ - ci[q]*s_;
        im += cr[q]*s_ + ci[q]*c_;
        m += y; if (m >= 192) m -= 192;
    }
    long o = (((long)p*HH + y)*WF + k)*2;
    G[o] = re*INV_SQRT_N; G[o+1] = im*INV_SQRT_N;
}

// ---------------- inverse row irfft: complex 97 -> real 192 ----------------
__global__ void k_invrow(const float* __restrict__ G, const float* __restrict__ tw,
                         float* __restrict__ out){
    __shared__ float gr[WF], gi[WF], tc[192], ts[192];
    long blk = blockIdx.x;                        // plane*HH + y
    int t = threadIdx.x;                          // 192
    if (t < WF){
        gr[t] = G[(blk*WF + t)*2];
        gi[t] = G[(blk*WF + t)*2 + 1];
    }
    tc[t] = tw[t]; ts[t] = tw[192+t];
    __syncthreads();
    int n = t;
    float acc = gr[0] + ((n & 1) ? -gr[96] : gr[96]);
    int m = 0;
    for (int k = 1; k < 96; k++){
        m += n; if (m >= 192) m -= 192;
        acc += 2.0f*(gr[k]*tc[m] - gi[k]*ts[m]);
    }
    out[blk*WW + n] = acc*INV_SQRT_N;
}

extern "C" void kernel_launch(void* const* d_in, const int* in_sizes, int n_in,
                              void* d_out, int out_size, void* d_ws, size_t ws_size,
                              hipStream_t stream){
    const float* x   = (const float*)d_in[0];
    const float* dt  = (const float*)d_in[1];
    const float* w1  = (const float*)d_in[2];
    const float* b1  = (const float*)d_in[3];
    const float* w2  = (const float*)d_in[4];
    const float* b2  = (const float*)d_in[5];
    const float* c1w = (const float*)d_in[6];
    const float* c1b = (const float*)d_in[7];
    const float* c2w = (const float*)d_in[8];
    const float* c2b = (const float*)d_in[9];
    const float* c3w = (const float*)d_in[10];
    // c3b unused: d(sum)/dx has no dependence on the final bias.
    float* out = (float*)d_out;
    float* ws  = (float*)d_ws;

    const long RSZ = (long)NPLANE*FPIX*2;        // 19,070,976 floats
    float* R1  = ws;
    float* R2  = ws + RSZ;
    float* AB  = R2 + RSZ;                       // NB*NC*FPIX*2 = 595,968
    float* TW  = AB + (long)NB*NC*FPIX*2;        // 384
    float* NRM = TW + 384;                       // 128
    // total ≈ 155 MB of d_ws

    k_tab<<<2, 128, 0, stream>>>(TW, NRM);
    k_A<<<(FPIX + 255)/256, 256, 0, stream>>>(dt, w1, b1, w2, b2, AB);

    for (int ch = 0; ch < NIMG/CHUNK; ch++){
        int img0 = ch*CHUNK;
        float* ys1 = R2;
        float* dy1 = R2 + (long)CHUNK*NC2*PIX;
        float* g2  = R1;
        float* g1  = R2;   // overwrites ys1 (dead by then); reads dy1 pointwise
        k_conv1  <<<CHUNK*NC2*PIX/256, 256, 0, stream>>>(x, c1w, c1b, ys1, dy1, img0);
        k_conv2g2<<<CHUNK*NC2*PIX/256, 256, 0, stream>>>(ys1, c2w, c2b, c3w, g2);
        k_g1     <<<CHUNK*NC2*PIX/256, 256, 0, stream>>>(g2, dy1, c2w, g1);
        k_xp     <<<CHUNK*NC*PIX/256,  256, 0, stream>>>(x, g1, c1w, dt, out, img0);
    }

    k_rowfft<<<NPLANE*HH, 128, 0, stream>>>(out, TW, R1);
    k_colfft<<<NPLANE*WF, 192, 0, stream>>>(R1, TW, R2);
    k_constrain<<<NIMG*FPIX/256, 256, 0, stream>>>(R2);
    k_norm<<<dim3(128, NIMG), 256, 0, stream>>>(R2, NRM);
    k_scan<<<NB*NC*FPIX/256, 256, 0, stream>>>(R2, AB, R1);
    k_constrain<<<NIMG*FPIX/256, 256, 0, stream>>>(R1);
    k_norm<<<dim3(128, NIMG), 256, 0, stream>>>(R1, NRM + NIMG);
    k_invcol<<<NPLANE*WF, 192, 0, stream>>>(R1, TW, NRM, R2);
    k_invrow<<<NPLANE*HH, 192, 0, stream>>>(R2, TW, out);
}

// Round 2
// 2765.355 us; speedup vs baseline: 3.3386x; 3.3386x over previous
//
#include <hip/hip_runtime.h>
#include <math.h>

#define HH 192
#define WW 192
#define WF 97
#define NC 8
#define NC2 16
#define NT 32
#define NB 2
#define NIMG (NB*NT)        // 64
#define NPLANE (NIMG*NC)    // 512
#define PIX (HH*WW)         // 36864
#define FPIX (HH*WF)        // 18624
#define CHUNK 16            // images per conv chunk
#define NG 13               // column groups of 8 (8*12+1 = 97)
#define INV_SQRT_N 0.07216878364870322f   // 1/sqrt(192)

// ---------------- tables + norm zero ----------------
__global__ void k_tab(float* tw, float* nrm){
    int i = blockIdx.x*blockDim.x + threadIdx.x;
    if (i < 192){
        double ang = 6.283185307179586476925286766559 * (double)i / 192.0;
        tw[i]       = (float)cos(ang);
        tw[192 + i] = (float)sin(ang);
    }
    if (i < 128) nrm[i] = 0.0f;
}

// ---------------- A = exp(i*omega*dt) via MLP ----------------
__global__ void k_A(const float* __restrict__ dt, const float* __restrict__ w1,
                    const float* __restrict__ b1, const float* __restrict__ w2,
                    const float* __restrict__ b2, float* __restrict__ Abuf){
    int idx = blockIdx.x*blockDim.x + threadIdx.x;
    if (idx >= FPIX) return;
    int i = idx / WF, j = idx % WF;
    float ky = (float)(i < 96 ? i : i - 192) / 192.0f;
    float kx = (float)j / 192.0f;
    float lp[NC];
    #pragma unroll
    for (int c = 0; c < NC; c++) lp[c] = b2[c];
    for (int jh = 0; jh < 64; jh++){
        float z  = ky*w1[jh] + kx*w1[64+jh] + b1[jh];
        float sg = 1.0f/(1.0f + expf(-z));
        float h  = z*sg;
        #pragma unroll
        for (int c = 0; c < NC; c++) lp[c] += h * w2[jh*NC + c];
    }
    float kph = sqrtf(ky*ky + kx*kx);
    for (int b = 0; b < NB; b++){
        float d = dt[b];
        #pragma unroll
        for (int c = 0; c < NC; c++){
            float ph = (lp[c] + kph) * d;
            float s, cn;
            sincosf(ph, &s, &cn);
            long o = (((long)(b*NC + c))*FPIX + idx) * 2;
            Abuf[o]   = cn;
            Abuf[o+1] = s;
        }
    }
}

// ================= LDS-tiled convolutions =================
// Block = 256 threads = one 16x16 output tile of one image. Full input tile
// (all in-channels, 18x18 with halo) + all weights staged in LDS.

__global__ void k_conv1_t(const float* __restrict__ x, const float* __restrict__ c1w,
                          const float* __restrict__ c1b, float* __restrict__ ys1,
                          float* __restrict__ dy1, int img0){
    __shared__ float tile[NC][18][18];     // 10.4 KB
    __shared__ float wl[NC2*NC*9];         // 4.6 KB
    int bid = blockIdx.x;
    int tx0 = (bid % 12)*16, ty0 = ((bid/12) % 12)*16;
    int il = bid / 144;
    int img = img0 + il;
    int tid = threadIdx.x;
    for (int i = tid; i < NC2*NC*9; i += 256) wl[i] = c1w[i];
    const float* xb = x + (long)img*NC*PIX;
    for (int idx = tid; idx < NC*324; idx += 256){
        int c = idx / 324, r = idx % 324;
        int iy = r/18, ix = r%18;
        int gy = ty0 + iy - 1, gx = tx0 + ix - 1;
        float v = 0.f;
        if (gy >= 0 && gy < HH && gx >= 0 && gx < WW) v = xb[c*PIX + gy*WW + gx];
        tile[c][iy][ix] = v;
    }
    __syncthreads();
    int ty = tid/16, tx = tid%16;
    float acc[NC2];
    #pragma unroll
    for (int o = 0; o < NC2; o++) acc[o] = c1b[o];
    for (int c = 0; c < NC; c++){
        #pragma unroll
        for (int dy = 0; dy < 3; dy++){
            #pragma unroll
            for (int dx = 0; dx < 3; dx++){
                float v = tile[c][ty+dy][tx+dx];
                #pragma unroll
                for (int o = 0; o < NC2; o++)
                    acc[o] += wl[(o*NC+c)*9 + dy*3+dx] * v;
            }
        }
    }
    long base = (long)il*NC2*PIX + (ty0+ty)*WW + (tx0+tx);
    #pragma unroll
    for (int o = 0; o < NC2; o++){
        float y = acc[o];
        float sg = 1.f/(1.f + expf(-y));
        ys1[base + (long)o*PIX] = y*sg;
        dy1[base + (long)o*PIX] = sg*(1.f + y*(1.f - sg));
    }
}

__global__ void k_conv2g2_t(const float* __restrict__ ys1, const float* __restrict__ c2w,
                            const float* __restrict__ c2b, const float* __restrict__ c3w,
                            float* __restrict__ g2){
    __shared__ float tile[NC2][18][18];    // 20.7 KB
    __shared__ float wl[NC2*NC2*9];        // 9.2 KB
    int bid = blockIdx.x;
    int tx0 = (bid % 12)*16, ty0 = ((bid/12) % 12)*16;
    int il = bid / 144;
    int tid = threadIdx.x;
    for (int i = tid; i < NC2*NC2*9; i += 256) wl[i] = c2w[i];
    const float* yb = ys1 + (long)il*NC2*PIX;
    for (int idx = tid; idx < NC2*324; idx += 256){
        int c = idx / 324, r = idx % 324;
        int iy = r/18, ix = r%18;
        int gy = ty0 + iy - 1, gx = tx0 + ix - 1;
        float v = 0.f;
        if (gy >= 0 && gy < HH && gx >= 0 && gx < WW) v = yb[(long)c*PIX + gy*WW + gx];
        tile[c][iy][ix] = v;
    }
    __syncthreads();
    int ty = tid/16, tx = tid%16;
    float acc[NC2];
    #pragma unroll
    for (int o = 0; o < NC2; o++) acc[o] = c2b[o];
    for (int c = 0; c < NC2; c++){
        #pragma unroll
        for (int dy = 0; dy < 3; dy++){
            #pragma unroll
            for (int dx = 0; dx < 3; dx++){
                float v = tile[c][ty+dy][tx+dx];
                #pragma unroll
                for (int o = 0; o < NC2; o++)
                    acc[o] += wl[(o*NC2+c)*9 + dy*3+dx] * v;
            }
        }
    }
    long base = (long)il*NC2*PIX + (ty0+ty)*WW + (tx0+tx);
    #pragma unroll
    for (int o = 0; o < NC2; o++){
        float y = acc[o];
        float sg = 1.f/(1.f + expf(-y));
        float ds = sg*(1.f + y*(1.f - sg));
        float s3 = 0.f;
        #pragma unroll
        for (int q = 0; q < NC; q++) s3 += c3w[q*NC2 + o];
        g2[base + (long)o*PIX] = ds * s3;
    }
}

__global__ void k_g1_t(const float* __restrict__ g2, const float* __restrict__ dy1,
                       const float* __restrict__ c2w, float* __restrict__ g1){
    __shared__ float tile[NC2][18][18];
    __shared__ float wl[NC2*NC2*9];
    int bid = blockIdx.x;
    int tx0 = (bid % 12)*16, ty0 = ((bid/12) % 12)*16;
    int il = bid / 144;
    int tid = threadIdx.x;
    for (int i = tid; i < NC2*NC2*9; i += 256) wl[i] = c2w[i];
    const float* gb = g2 + (long)il*NC2*PIX;
    for (int idx = tid; idx < NC2*324; idx += 256){
        int c = idx / 324, r = idx % 324;
        int iy = r/18, ix = r%18;
        int gy = ty0 + iy - 1, gx = tx0 + ix - 1;
        float v = 0.f;
        if (gy >= 0 && gy < HH && gx >= 0 && gx < WW) v = gb[(long)c*PIX + gy*WW + gx];
        tile[c][iy][ix] = v;
    }
    __syncthreads();
    int ty = tid/16, tx = tid%16;
    float acc[NC2];
    #pragma unroll
    for (int o = 0; o < NC2; o++) acc[o] = 0.f;
    for (int c2 = 0; c2 < NC2; c2++){
        #pragma unroll
        for (int dy = 0; dy < 3; dy++){
            #pragma unroll
            for (int dx = 0; dx < 3; dx++){
                float v = tile[c2][ty+2-dy][tx+2-dx];   // transpose conv
                #pragma unroll
                for (int c1 = 0; c1 < NC2; c1++)
                    acc[c1] += wl[(c2*NC2+c1)*9 + dy*3+dx] * v;
            }
        }
    }
    long base = (long)il*NC2*PIX + (ty0+ty)*WW + (tx0+tx);
    #pragma unroll
    for (int c1 = 0; c1 < NC2; c1++)
        g1[base + (long)c1*PIX] = acc[c1] * dy1[base + (long)c1*PIX];
}

__global__ void k_xp_t(const float* __restrict__ x, const float* __restrict__ g1,
                       const float* __restrict__ c1w, const float* __restrict__ dt,
                       float* __restrict__ xp, int img0){
    __shared__ float tile[NC2][18][18];
    __shared__ float wl[NC2*NC*9];
    int bid = blockIdx.x;
    int tx0 = (bid % 12)*16, ty0 = ((bid/12) % 12)*16;
    int il = bid / 144;
    int img = img0 + il;
    int b = img / NT;
    int tid = threadIdx.x;
    for (int i = tid; i < NC2*NC*9; i += 256) wl[i] = c1w[i];
    const float* gb = g1 + (long)il*NC2*PIX;
    for (int idx = tid; idx < NC2*324; idx += 256){
        int c = idx / 324, r = idx % 324;
        int iy = r/18, ix = r%18;
        int gy = ty0 + iy - 1, gx = tx0 + ix - 1;
        float v = 0.f;
        if (gy >= 0 && gy < HH && gx >= 0 && gx < WW) v = gb[(long)c*PIX + gy*WW + gx];
        tile[c][iy][ix] = v;
    }
    __syncthreads();
    int ty = tid/16, tx = tid%16;
    float acc[NC];
    #pragma unroll
    for (int c = 0; c < NC; c++) acc[c] = 0.f;
    for (int o = 0; o < NC2; o++){
        #pragma unroll
        for (int dy = 0; dy < 3; dy++){
            #pragma unroll
            for (int dx = 0; dx < 3; dx++){
                float v = tile[o][ty+2-dy][tx+2-dx];    // transpose conv
                #pragma unroll
                for (int c = 0; c < NC; c++)
                    acc[c] += wl[(o*NC+c)*9 + dy*3+dx] * v;
            }
        }
    }
    float d = dt[b];
    long gi = ((long)img*NC)*PIX + (ty0+ty)*WW + (tx0+tx);
    #pragma unroll
    for (int c = 0; c < NC; c++)
        xp[gi + (long)c*PIX] = x[gi + (long)c*PIX] + d*acc[c];
}

// ---------------- forward row rfft: real 192 -> complex 97 (unchanged) -----
__global__ void k_rowfft(const float* __restrict__ xp, const float* __restrict__ tw,
                         float* __restrict__ R){
    __shared__ float row[WW], tc[192], ts[192];
    long blk = blockIdx.x;                        // plane*HH + y
    const float* src = xp + blk*WW;
    for (int t = threadIdx.x; t < 192; t += blockDim.x){
        row[t] = src[t]; tc[t] = tw[t]; ts[t] = tw[192+t];
    }
    __syncthreads();
    int k = threadIdx.x;
    if (k < WF){
        float re = 0.0f, im = 0.0f; int m = 0;
        for (int x2 = 0; x2 < WW; x2++){
            float v = row[x2];
            re += v*tc[m]; im -= v*ts[m];
            m += k; if (m >= 192) m -= 192;
        }
        float* dst = R + (blk*WF + k)*2;
        dst[0] = re*INV_SQRT_N; dst[1] = im*INV_SQRT_N;
    }
}

// ========== two-stage column FFT: 192 = 16 x 12, 8 columns per block =======
// DIRSGN=-1 forward (e^{-i}), +1 inverse (e^{+i}); RESCALE folds energy norm.
template<int DIRSGN, bool RESCALE>
__global__ void k_cfft(const float* __restrict__ in, const float* __restrict__ tw,
                       const float* __restrict__ nrm, float* __restrict__ out){
    __shared__ float2 C[HH][9];        // input columns, padded: 13.8 KB
    __shared__ float2 A[16][12][9];    // stage-1 result:      13.8 KB
    __shared__ float twc[192], tws[192];
    const float sgn = (DIRSGN > 0) ? 1.f : -1.f;
    int p  = blockIdx.x / NG;          // plane
    int g  = blockIdx.x % NG;
    int j0 = g*8;
    int t  = threadIdx.x;              // 192
    twc[t] = tw[t]; tws[t] = tw[192+t];
    float scale = 1.f;
    if (RESCALE){
        int bt = p / NC;
        scale = sqrtf(nrm[bt]) / (sqrtf(nrm[64+bt]) + 1e-6f);
    }
    const float2* src = ((const float2*)in) + ((long)p*HH + t)*WF + j0;
    #pragma unroll
    for (int jj = 0; jj < 8; jj++){
        float2 v = {0.f, 0.f};
        if (j0 + jj < WF) v = src[jj];
        v.x *= scale; v.y *= scale;
        C[t][jj] = v;
    }
    __syncthreads();
    // stage 1: A[k1][n2] = tw192(n2*k1) * sum_{n1<16} C[12*n1+n2] * W16^{n1*k1}
    {
        int k1 = t / 12, n2 = t % 12;
        int step = 12*k1;                       // < 192
        int mI = n2*k1;                         // < 192
        float ic = twc[mI], is_ = sgn*tws[mI];
        #pragma unroll
        for (int jj = 0; jj < 8; jj++){
            float re = 0.f, im = 0.f; int m = 0;
            #pragma unroll
            for (int n1 = 0; n1 < 16; n1++){
                float2 v = C[12*n1 + n2][jj];
                float c_ = twc[m], s_ = sgn*tws[m];
                re += v.x*c_ - v.y*s_;
                im += v.x*s_ + v.y*c_;
                m += step; if (m >= 192) m -= 192;
            }
            float2 a;
            a.x = re*ic - im*is_;
            a.y = re*is_ + im*ic;
            A[k1][n2][jj] = a;
        }
    }
    __syncthreads();
    // stage 2: X[k1 + 16*k2] = sum_{n2<12} A[k1][n2] * W12^{n2*k2};  ky == t
    {
        int k1 = t % 16, k2 = t / 16;
        int step = 16*k2;                       // < 192
        float2* dst = ((float2*)out) + ((long)p*HH + t)*WF + j0;
        #pragma unroll
        for (int jj = 0; jj < 8; jj++){
            float re = 0.f, im = 0.f; int m = 0;
            #pragma unroll
            for (int n2 = 0; n2 < 12; n2++){
                float2 a = A[k1][n2][jj];
                float c_ = twc[m], s_ = sgn*tws[m];
                re += a.x*c_ - a.y*s_;
                im += a.x*s_ + a.y*c_;
                m += step; if (m >= 192) m -= 192;
            }
            if (j0 + jj < WF){
                float2 r; r.x = re*INV_SQRT_N; r.y = im*INV_SQRT_N;
                dst[jj] = r;
            }
        }
    }
}

// ---------------- divergence projection (channels 0,1) ----------------
__global__ void k_constrain(float* __restrict__ F){
    int idx = blockIdx.x*256 + threadIdx.x;       // NIMG*FPIX exact
    int j = idx % WF; int tmp = idx / WF;
    int i = tmp % HH; int bt = tmp / HH;
    float ky = (float)(i < 96 ? i : i - 192)/192.0f;
    float kx = (float)j/192.0f;
    float k2 = ky*ky + kx*kx;
    if (i == 0 && j == 0) k2 = 1.0f;
    long ui = ((((long)bt*NC + 0)*HH + i)*WF + j)*2;
    long vi = ((((long)bt*NC + 1)*HH + i)*WF + j)*2;
    float ur = F[ui], um = F[ui+1], vr = F[vi], vm = F[vi+1];
    float dr = (ky*ur + kx*vr)/k2;
    float di = (ky*um + kx*vm)/k2;
    F[ui]   = ur - ky*dr;  F[ui+1] = um - ky*di;
    F[vi]   = vr - kx*dr;  F[vi+1] = vm - kx*di;
}

// ---------------- per-(b,t) energy reduction ----------------
__global__ void k_norm(const float* __restrict__ F, float* __restrict__ dst){
    int bt = blockIdx.y;
    __shared__ float red[256];
    float s = 0.0f;
    const float* base = F + (long)bt*NC*FPIX*2;
    for (int e = blockIdx.x*256 + threadIdx.x; e < NC*FPIX; e += gridDim.x*256){
        float re = base[(long)e*2], im = base[(long)e*2 + 1];
        s += re*re + im*im;
    }
    red[threadIdx.x] = s; __syncthreads();
    for (int st = 128; st > 0; st >>= 1){
        if (threadIdx.x < st) red[threadIdx.x] += red[threadIdx.x + st];
        __syncthreads();
    }
    if (threadIdx.x == 0) atomicAdd(&dst[bt], red[0]);
}

// ---------------- time recurrence h[t] = A*h[t-1] + X[t] ----------------
__global__ void k_scan(const float* __restrict__ Xf, const float* __restrict__ Abuf,
                       float* __restrict__ Hf){
    int idx = blockIdx.x*256 + threadIdx.x;       // NB*NC*FPIX exact
    int f = idx % FPIX; int tmp = idx / FPIX;
    int c = tmp % NC; int b = tmp / NC;
    long ao = (((long)(b*NC + c))*FPIX + f)*2;
    float ar = Abuf[ao], ai = Abuf[ao+1];
    float hr = 0.0f, hi = 0.0f;
    for (int t = 0; t < NT; t++){
        long e = (((((long)b*NT + t)*NC + c)*FPIX) + f)*2;
        float xr = Xf[e], xi = Xf[e+1];
        float nr = ar*hr - ai*hi + xr;
        float ni = ar*hi + ai*hr + xi;
        hr = nr; hi = ni;
        Hf[e] = hr; Hf[e+1] = hi;
    }
}

// ---------------- inverse row irfft: complex 97 -> real 192 (unchanged) ----
__global__ void k_invrow(const float* __restrict__ G, const float* __restrict__ tw,
                         float* __restrict__ out){
    __shared__ float gr[WF], gi[WF], tc[192], ts[192];
    long blk = blockIdx.x;                        // plane*HH + y
    int t = threadIdx.x;                          // 192
    if (t < WF){
        gr[t] = G[(blk*WF + t)*2];
        gi[t] = G[(blk*WF + t)*2 + 1];
    }
    tc[t] = tw[t]; ts[t] = tw[192+t];
    __syncthreads();
    int n = t;
    float acc = gr[0] + ((n & 1) ? -gr[96] : gr[96]);
    int m = 0;
    for (int k = 1; k < 96; k++){
        m += n; if (m >= 192) m -= 192;
        acc += 2.0f*(gr[k]*tc[m] - gi[k]*ts[m]);
    }
    out[blk*WW + n] = acc*INV_SQRT_N;
}

extern "C" void kernel_launch(void* const* d_in, const int* in_sizes, int n_in,
                              void* d_out, int out_size, void* d_ws, size_t ws_size,
                              hipStream_t stream){
    const float* x   = (const float*)d_in[0];
    const float* dt  = (const float*)d_in[1];
    const float* w1  = (const float*)d_in[2];
    const float* b1  = (const float*)d_in[3];
    const float* w2  = (const float*)d_in[4];
    const float* b2  = (const float*)d_in[5];
    const float* c1w = (const float*)d_in[6];
    const float* c1b = (const float*)d_in[7];
    const float* c2w = (const float*)d_in[8];
    const float* c2b = (const float*)d_in[9];
    const float* c3w = (const float*)d_in[10];
    float* out = (float*)d_out;
    float* ws  = (float*)d_ws;

    const long RSZ = (long)NPLANE*FPIX*2;        // 19,070,976 floats
    float* R1  = ws;
    float* R2  = ws + RSZ;
    float* AB  = R2 + RSZ;
    float* TW  = AB + (long)NB*NC*FPIX*2;
    float* NRM = TW + 384;

    k_tab<<<2, 128, 0, stream>>>(TW, NRM);
    k_A<<<(FPIX + 255)/256, 256, 0, stream>>>(dt, w1, b1, w2, b2, AB);

    for (int ch = 0; ch < NIMG/CHUNK; ch++){
        int img0 = ch*CHUNK;
        float* ys1 = R2;
        float* dy1 = R2 + (long)CHUNK*NC2*PIX;
        float* g2  = R1;
        float* g1  = R2;   // overwrites ys1 (dead by then); reads dy1 pointwise
        int nb = CHUNK*144;                      // 2304 tile-blocks
        k_conv1_t  <<<nb, 256, 0, stream>>>(x, c1w, c1b, ys1, dy1, img0);
        k_conv2g2_t<<<nb, 256, 0, stream>>>(ys1, c2w, c2b, c3w, g2);
        k_g1_t     <<<nb, 256, 0, stream>>>(g2, dy1, c2w, g1);
        k_xp_t     <<<nb, 256, 0, stream>>>(x, g1, c1w, dt, out, img0);
    }

    k_rowfft<<<NPLANE*HH, 128, 0, stream>>>(out, TW, R1);
    k_cfft<-1,false><<<NPLANE*NG, 192, 0, stream>>>(R1, TW, NRM, R2);
    k_constrain<<<NIMG*FPIX/256, 256, 0, stream>>>(R2);
    k_norm<<<dim3(128, NIMG), 256, 0, stream>>>(R2, NRM);
    k_scan<<<NB*NC*FPIX/256, 256, 0, stream>>>(R2, AB, R1);
    k_constrain<<<NIMG*FPIX/256, 256, 0, stream>>>(R1);
    k_norm<<<dim3(128, NIMG), 256, 0, stream>>>(R1, NRM + NIMG);
    k_cfft<+1,true><<<NPLANE*NG, 192, 0, stream>>>(R1, TW, NRM, R2);
    k_invrow<<<NPLANE*HH, 192, 0, stream>>>(R2, TW, out);
}

// Round 4
// 1764.202 us; speedup vs baseline: 5.2333x; 1.5675x over previous
//
#include <hip/hip_runtime.h>
#include <math.h>

#define HH 192
#define WW 192
#define WF 97
#define NC 8
#define NC2 16
#define NT 32
#define NB 2
#define NIMG (NB*NT)        // 64
#define NPLANE (NIMG*NC)    // 512
#define PIX (HH*WW)         // 36864
#define FPIX (HH*WF)        // 18624
#define CHUNK 16            // images per conv chunk
#define NG 13               // column groups of 8 (8*12+1 = 97)
#define INV_SQRT_N 0.07216878364870322f   // 1/sqrt(192)

// ---------------- tables + norm zero ----------------
__global__ void k_tab(float* tw, float* nrm){
    int i = blockIdx.x*blockDim.x + threadIdx.x;
    if (i < 192){
        double ang = 6.283185307179586476925286766559 * (double)i / 192.0;
        tw[i]       = (float)cos(ang);
        tw[192 + i] = (float)sin(ang);
    }
    if (i < 128) nrm[i] = 0.0f;
}

// ---------------- A = exp(i*omega*dt) via MLP ----------------
__global__ void k_A(const float* __restrict__ dt, const float* __restrict__ w1,
                    const float* __restrict__ b1, const float* __restrict__ w2,
                    const float* __restrict__ b2, float* __restrict__ Abuf){
    int idx = blockIdx.x*blockDim.x + threadIdx.x;
    if (idx >= FPIX) return;
    int i = idx / WF, j = idx % WF;
    float ky = (float)(i < 96 ? i : i - 192) / 192.0f;
    float kx = (float)j / 192.0f;
    float lp[NC];
    #pragma unroll
    for (int c = 0; c < NC; c++) lp[c] = b2[c];
    for (int jh = 0; jh < 64; jh++){
        float z  = ky*w1[jh] + kx*w1[64+jh] + b1[jh];
        float sg = 1.0f/(1.0f + expf(-z));
        float h  = z*sg;
        #pragma unroll
        for (int c = 0; c < NC; c++) lp[c] += h * w2[jh*NC + c];
    }
    float kph = sqrtf(ky*ky + kx*kx);
    for (int b = 0; b < NB; b++){
        float d = dt[b];
        #pragma unroll
        for (int c = 0; c < NC; c++){
            float ph = (lp[c] + kph) * d;
            float s, cn;
            sincosf(ph, &s, &cn);
            long o = (((long)(b*NC + c))*FPIX + idx) * 2;
            Abuf[o]   = cn;
            Abuf[o+1] = s;
        }
    }
}

// ================= LDS-tiled convolutions =================
__global__ void k_conv1_t(const float* __restrict__ x, const float* __restrict__ c1w,
                          const float* __restrict__ c1b, float* __restrict__ ys1,
                          float* __restrict__ dy1, int img0){
    __shared__ float tile[NC][18][18];
    __shared__ float wl[NC2*NC*9];
    int bid = blockIdx.x;
    int tx0 = (bid % 12)*16, ty0 = ((bid/12) % 12)*16;
    int il = bid / 144;
    int img = img0 + il;
    int tid = threadIdx.x;
    for (int i = tid; i < NC2*NC*9; i += 256) wl[i] = c1w[i];
    const float* xb = x + (long)img*NC*PIX;
    for (int idx = tid; idx < NC*324; idx += 256){
        int c = idx / 324, r = idx % 324;
        int iy = r/18, ix = r%18;
        int gy = ty0 + iy - 1, gx = tx0 + ix - 1;
        float v = 0.f;
        if (gy >= 0 && gy < HH && gx >= 0 && gx < WW) v = xb[c*PIX + gy*WW + gx];
        tile[c][iy][ix] = v;
    }
    __syncthreads();
    int ty = tid/16, tx = tid%16;
    float acc[NC2];
    #pragma unroll
    for (int o = 0; o < NC2; o++) acc[o] = c1b[o];
    for (int c = 0; c < NC; c++){
        #pragma unroll
        for (int dy = 0; dy < 3; dy++){
            #pragma unroll
            for (int dx = 0; dx < 3; dx++){
                float v = tile[c][ty+dy][tx+dx];
                #pragma unroll
                for (int o = 0; o < NC2; o++)
                    acc[o] += wl[(o*NC+c)*9 + dy*3+dx] * v;
            }
        }
    }
    long base = (long)il*NC2*PIX + (ty0+ty)*WW + (tx0+tx);
    #pragma unroll
    for (int o = 0; o < NC2; o++){
        float y = acc[o];
        float sg = 1.f/(1.f + expf(-y));
        ys1[base + (long)o*PIX] = y*sg;
        dy1[base + (long)o*PIX] = sg*(1.f + y*(1.f - sg));
    }
}

__global__ void k_conv2g2_t(const float* __restrict__ ys1, const float* __restrict__ c2w,
                            const float* __restrict__ c2b, const float* __restrict__ c3w,
                            float* __restrict__ g2){
    __shared__ float tile[NC2][18][18];
    __shared__ float wl[NC2*NC2*9];
    int bid = blockIdx.x;
    int tx0 = (bid % 12)*16, ty0 = ((bid/12) % 12)*16;
    int il = bid / 144;
    int tid = threadIdx.x;
    for (int i = tid; i < NC2*NC2*9; i += 256) wl[i] = c2w[i];
    const float* yb = ys1 + (long)il*NC2*PIX;
    for (int idx = tid; idx < NC2*324; idx += 256){
        int c = idx / 324, r = idx % 324;
        int iy = r/18, ix = r%18;
        int gy = ty0 + iy - 1, gx = tx0 + ix - 1;
        float v = 0.f;
        if (gy >= 0 && gy < HH && gx >= 0 && gx < WW) v = yb[(long)c*PIX + gy*WW + gx];
        tile[c][iy][ix] = v;
    }
    __syncthreads();
    int ty = tid/16, tx = tid%16;
    float acc[NC2];
    #pragma unroll
    for (int o = 0; o < NC2; o++) acc[o] = c2b[o];
    for (int c = 0; c < NC2; c++){
        #pragma unroll
        for (int dy = 0; dy < 3; dy++){
            #pragma unroll
            for (int dx = 0; dx < 3; dx++){
                float v = tile[c][ty+dy][tx+dx];
                #pragma unroll
                for (int o = 0; o < NC2; o++)
                    acc[o] += wl[(o*NC2+c)*9 + dy*3+dx] * v;
            }
        }
    }
    long base = (long)il*NC2*PIX + (ty0+ty)*WW + (tx0+tx);
    #pragma unroll
    for (int o = 0; o < NC2; o++){
        float y = acc[o];
        float sg = 1.f/(1.f + expf(-y));
        float ds = sg*(1.f + y*(1.f - sg));
        float s3 = 0.f;
        #pragma unroll
        for (int q = 0; q < NC; q++) s3 += c3w[q*NC2 + o];
        g2[base + (long)o*PIX] = ds * s3;
    }
}

__global__ void k_g1_t(const float* __restrict__ g2, const float* __restrict__ dy1,
                       const float* __restrict__ c2w, float* __restrict__ g1){
    __shared__ float tile[NC2][18][18];
    __shared__ float wl[NC2*NC2*9];
    int bid = blockIdx.x;
    int tx0 = (bid % 12)*16, ty0 = ((bid/12) % 12)*16;
    int il = bid / 144;
    int tid = threadIdx.x;
    for (int i = tid; i < NC2*NC2*9; i += 256) wl[i] = c2w[i];
    const float* gb = g2 + (long)il*NC2*PIX;
    for (int idx = tid; idx < NC2*324; idx += 256){
        int c = idx / 324, r = idx % 324;
        int iy = r/18, ix = r%18;
        int gy = ty0 + iy - 1, gx = tx0 + ix - 1;
        float v = 0.f;
        if (gy >= 0 && gy < HH && gx >= 0 && gx < WW) v = gb[(long)c*PIX + gy*WW + gx];
        tile[c][iy][ix] = v;
    }
    __syncthreads();
    int ty = tid/16, tx = tid%16;
    float acc[NC2];
    #pragma unroll
    for (int o = 0; o < NC2; o++) acc[o] = 0.f;
    for (int c2 = 0; c2 < NC2; c2++){
        #pragma unroll
        for (int dy = 0; dy < 3; dy++){
            #pragma unroll
            for (int dx = 0; dx < 3; dx++){
                float v = tile[c2][ty+2-dy][tx+2-dx];
                #pragma unroll
                for (int c1 = 0; c1 < NC2; c1++)
                    acc[c1] += wl[(c2*NC2+c1)*9 + dy*3+dx] * v;
            }
        }
    }
    long base = (long)il*NC2*PIX + (ty0+ty)*WW + (tx0+tx);
    #pragma unroll
    for (int c1 = 0; c1 < NC2; c1++)
        g1[base + (long)c1*PIX] = acc[c1] * dy1[base + (long)c1*PIX];
}

__global__ void k_xp_t(const float* __restrict__ x, const float* __restrict__ g1,
                       const float* __restrict__ c1w, const float* __restrict__ dt,
                       float* __restrict__ xp, int img0){
    __shared__ float tile[NC2][18][18];
    __shared__ float wl[NC2*NC*9];
    int bid = blockIdx.x;
    int tx0 = (bid % 12)*16, ty0 = ((bid/12) % 12)*16;
    int il = bid / 144;
    int img = img0 + il;
    int b = img / NT;
    int tid = threadIdx.x;
    for (int i = tid; i < NC2*NC*9; i += 256) wl[i] = c1w[i];
    const float* gb = g1 + (long)il*NC2*PIX;
    for (int idx = tid; idx < NC2*324; idx += 256){
        int c = idx / 324, r = idx % 324;
        int iy = r/18, ix = r%18;
        int gy = ty0 + iy - 1, gx = tx0 + ix - 1;
        float v = 0.f;
        if (gy >= 0 && gy < HH && gx >= 0 && gx < WW) v = gb[(long)c*PIX + gy*WW + gx];
        tile[c][iy][ix] = v;
    }
    __syncthreads();
    int ty = tid/16, tx = tid%16;
    float acc[NC];
    #pragma unroll
    for (int c = 0; c < NC; c++) acc[c] = 0.f;
    for (int o = 0; o < NC2; o++){
        #pragma unroll
        for (int dy = 0; dy < 3; dy++){
            #pragma unroll
            for (int dx = 0; dx < 3; dx++){
                float v = tile[o][ty+2-dy][tx+2-dx];
                #pragma unroll
                for (int c = 0; c < NC; c++)
                    acc[c] += wl[(o*NC+c)*9 + dy*3+dx] * v;
            }
        }
    }
    float d = dt[b];
    long gi = ((long)img*NC)*PIX + (ty0+ty)*WW + (tx0+tx);
    #pragma unroll
    for (int c = 0; c < NC; c++)
        xp[gi + (long)c*PIX] = x[gi + (long)c*PIX] + d*acc[c];
}

// ====== two-stage row rfft (192=16x12), 2 real rows packed per complex =====
__global__ void k_rowfft2(const float* __restrict__ xp, const float* __restrict__ tw,
                          float* __restrict__ R){
    __shared__ float2 C[192][9];       // input z / reused for Z
    __shared__ float2 A1[12][16][9];   // stage-1 result [n2][k1][jj]
    __shared__ float twc[192], tws[192];
    int p  = blockIdx.x / 12;
    int r0 = (blockIdx.x % 12)*16;
    int t  = threadIdx.x;
    twc[t] = tw[t]; tws[t] = tw[192+t];
    const float* base = xp + (long)p*PIX + (long)r0*WW;
    #pragma unroll
    for (int jj = 0; jj < 8; jj++){
        float2 z; z.x = base[(2*jj)*WW + t]; z.y = base[(2*jj+1)*WW + t];
        C[t][jj] = z;
    }
    __syncthreads();
    {   // stage 1
        int k1 = t / 12, n2 = t % 12;
        float wr[16], wi[16];
        int m = n2*k1 % 192, step = (12*k1) % 192;
        #pragma unroll
        for (int n1 = 0; n1 < 16; n1++){
            wr[n1] = twc[m]; wi[n1] = -tws[m];
            m += step; if (m >= 192) m -= 192;
        }
        #pragma unroll
        for (int jj = 0; jj < 8; jj++){
            float re = 0.f, im = 0.f;
            #pragma unroll
            for (int n1 = 0; n1 < 16; n1++){
                float2 v = C[12*n1 + n2][jj];
                re += v.x*wr[n1] - v.y*wi[n1];
                im += v.x*wi[n1] + v.y*wr[n1];
            }
            float2 a; a.x = re; a.y = im;
            A1[n2][k1][jj] = a;
        }
    }
    __syncthreads();
    {   // stage 2
        int k1 = t % 16, k2 = t / 16;
        float wr[12], wi[12];
        int m = 0, step = (16*k2) % 192;
        #pragma unroll
        for (int n2 = 0; n2 < 12; n2++){
            wr[n2] = twc[m]; wi[n2] = -tws[m];
            m += step; if (m >= 192) m -= 192;
        }
        #pragma unroll
        for (int jj = 0; jj < 8; jj++){
            float re = 0.f, im = 0.f;
            #pragma unroll
            for (int n2 = 0; n2 < 12; n2++){
                float2 a = A1[n2][k1][jj];
                re += a.x*wr[n2] - a.y*wi[n2];
                im += a.x*wi[n2] + a.y*wr[n2];
            }
            float2 z; z.x = re*INV_SQRT_N; z.y = im*INV_SQRT_N;
            C[t][jj] = z;
        }
    }
    __syncthreads();
    if (t < WF){                           // Hermitian unpack
        int t2 = (t == 0) ? 0 : 192 - t;
        float2* dst = ((float2*)R) + ((long)p*HH + r0)*WF + t;
        #pragma unroll
        for (int jj = 0; jj < 8; jj++){
            float2 u = C[t][jj], v = C[t2][jj];
            float2 A_; A_.x = 0.5f*(u.x + v.x); A_.y = 0.5f*(u.y - v.y);
            float2 B_; B_.x = 0.5f*(u.y + v.y); B_.y = -0.5f*(u.x - v.x);
            dst[(2*jj)*WF]   = A_;
            dst[(2*jj+1)*WF] = B_;
        }
    }
}

// ====== two-stage inverse row irfft, 2 spectra packed per complex ifft =====
// C2R convention: imaginary parts of DC (kx=0) and Nyquist (kx=96) bins are
// IGNORED (numpy/pocketfft). Must zero them here or they leak between the
// packed row pair (round-3 failure: absmax 0.117).
__global__ void k_invrow2(const float* __restrict__ G, const float* __restrict__ tw,
                          float* __restrict__ out){
    __shared__ float2 C[192][9];
    __shared__ float2 A1[12][16][9];
    __shared__ float twc[192], tws[192];
    int p  = blockIdx.x / 12;
    int r0 = (blockIdx.x % 12)*16;
    int t  = threadIdx.x;
    twc[t] = tw[t]; tws[t] = tw[192+t];
    const float2* Gb = ((const float2*)G) + ((long)p*HH + r0)*WF;
    int tt = (t <= 96) ? t : 192 - t;
    bool dcny = (t == 0) || (t == 96);
    #pragma unroll
    for (int jj = 0; jj < 8; jj++){
        float2 a = Gb[(2*jj)*WF + tt];
        float2 b = Gb[(2*jj+1)*WF + tt];
        if (dcny){ a.y = 0.f; b.y = 0.f; }
        float2 z;
        if (t <= 96){ z.x = a.x - b.y; z.y = a.y + b.x; }
        else        { z.x = a.x + b.y; z.y = b.x - a.y; }
        C[t][jj] = z;
    }
    __syncthreads();
    {   // stage 1 (e^{+i})
        int k1 = t / 12, n2 = t % 12;
        float wr[16], wi[16];
        int m = n2*k1 % 192, step = (12*k1) % 192;
        #pragma unroll
        for (int n1 = 0; n1 < 16; n1++){
            wr[n1] = twc[m]; wi[n1] = tws[m];
            m += step; if (m >= 192) m -= 192;
        }
        #pragma unroll
        for (int jj = 0; jj < 8; jj++){
            float re = 0.f, im = 0.f;
            #pragma unroll
            for (int n1 = 0; n1 < 16; n1++){
                float2 v = C[12*n1 + n2][jj];
                re += v.x*wr[n1] - v.y*wi[n1];
                im += v.x*wi[n1] + v.y*wr[n1];
            }
            float2 a; a.x = re; a.y = im;
            A1[n2][k1][jj] = a;
        }
    }
    __syncthreads();
    {   // stage 2 (e^{+i}): Re->rowA, Im->rowB
        int k1 = t % 16, k2 = t / 16;
        float wr[12], wi[12];
        int m = 0, step = (16*k2) % 192;
        #pragma unroll
        for (int n2 = 0; n2 < 12; n2++){
            wr[n2] = twc[m]; wi[n2] = tws[m];
            m += step; if (m >= 192) m -= 192;
        }
        float* ob = out + (long)p*PIX + (long)r0*WW;
        #pragma unroll
        for (int jj = 0; jj < 8; jj++){
            float re = 0.f, im = 0.f;
            #pragma unroll
            for (int n2 = 0; n2 < 12; n2++){
                float2 a = A1[n2][k1][jj];
                re += a.x*wr[n2] - a.y*wi[n2];
                im += a.x*wi[n2] + a.y*wr[n2];
            }
            ob[(2*jj)*WW + t]   = re*INV_SQRT_N;
            ob[(2*jj+1)*WW + t] = im*INV_SQRT_N;
        }
    }
}

// ========== two-stage column FFT: 192 = 16 x 12, 8 columns per block =======
template<int DIRSGN, bool RESCALE>
__global__ void k_cfft(const float* __restrict__ in, const float* __restrict__ tw,
                       const float* __restrict__ nrm, float* __restrict__ out){
    __shared__ float2 C[HH][9];
    __shared__ float2 A1[12][16][9];   // [n2][k1][jj]
    __shared__ float twc[192], tws[192];
    const float sgn = (DIRSGN > 0) ? 1.f : -1.f;
    int p  = blockIdx.x / NG;
    int g  = blockIdx.x % NG;
    int j0 = g*8;
    int t  = threadIdx.x;
    twc[t] = tw[t]; tws[t] = tw[192+t];
    float scale = 1.f;
    if (RESCALE){
        int bt = p / NC;
        scale = sqrtf(nrm[bt]) / (sqrtf(nrm[64+bt]) + 1e-6f);
    }
    const float2* src = ((const float2*)in) + ((long)p*HH + t)*WF + j0;
    #pragma unroll
    for (int jj = 0; jj < 8; jj++){
        float2 v = {0.f, 0.f};
        if (j0 + jj < WF) v = src[jj];
        v.x *= scale; v.y *= scale;
        C[t][jj] = v;
    }
    __syncthreads();
    {   // stage 1
        int k1 = t / 12, n2 = t % 12;
        float wr[16], wi[16];
        int m = n2*k1 % 192, step = (12*k1) % 192;
        #pragma unroll
        for (int n1 = 0; n1 < 16; n1++){
            wr[n1] = twc[m]; wi[n1] = sgn*tws[m];
            m += step; if (m >= 192) m -= 192;
        }
        #pragma unroll
        for (int jj = 0; jj < 8; jj++){
            float re = 0.f, im = 0.f;
            #pragma unroll
            for (int n1 = 0; n1 < 16; n1++){
                float2 v = C[12*n1 + n2][jj];
                re += v.x*wr[n1] - v.y*wi[n1];
                im += v.x*wi[n1] + v.y*wr[n1];
            }
            float2 a; a.x = re; a.y = im;
            A1[n2][k1][jj] = a;
        }
    }
    __syncthreads();
    {   // stage 2: ky == t
        int k1 = t % 16, k2 = t / 16;
        float wr[12], wi[12];
        int m = 0, step = (16*k2) % 192;
        #pragma unroll
        for (int n2 = 0; n2 < 12; n2++){
            wr[n2] = twc[m]; wi[n2] = sgn*tws[m];
            m += step; if (m >= 192) m -= 192;
        }
        float2* dst = ((float2*)out) + ((long)p*HH + t)*WF + j0;
        #pragma unroll
        for (int jj = 0; jj < 8; jj++){
            float re = 0.f, im = 0.f;
            #pragma unroll
            for (int n2 = 0; n2 < 12; n2++){
                float2 a = A1[n2][k1][jj];
                re += a.x*wr[n2] - a.y*wi[n2];
                im += a.x*wi[n2] + a.y*wr[n2];
            }
            if (j0 + jj < WF){
                float2 r; r.x = re*INV_SQRT_N; r.y = im*INV_SQRT_N;
                dst[jj] = r;
            }
        }
    }
}

// ---------------- divergence projection (channels 0,1) ----------------
__global__ void k_constrain(float* __restrict__ F){
    int idx = blockIdx.x*256 + threadIdx.x;
    int j = idx % WF; int tmp = idx / WF;
    int i = tmp % HH; int bt = tmp / HH;
    float ky = (float)(i < 96 ? i : i - 192)/192.0f;
    float kx = (float)j/192.0f;
    float k2 = ky*ky + kx*kx;
    if (i == 0 && j == 0) k2 = 1.0f;
    long ui = ((((long)bt*NC + 0)*HH + i)*WF + j)*2;
    long vi = ((((long)bt*NC + 1)*HH + i)*WF + j)*2;
    float ur = F[ui], um = F[ui+1], vr = F[vi], vm = F[vi+1];
    float dr = (ky*ur + kx*vr)/k2;
    float di = (ky*um + kx*vm)/k2;
    F[ui]   = ur - ky*dr;  F[ui+1] = um - ky*di;
    F[vi]   = vr - kx*dr;  F[vi+1] = vm - kx*di;
}

// ---------------- per-(b,t) energy reduction ----------------
__global__ void k_norm(const float* __restrict__ F, float* __restrict__ dst){
    int bt = blockIdx.y;
    __shared__ float red[256];
    float s = 0.0f;
    const float* base = F + (long)bt*NC*FPIX*2;
    for (int e = blockIdx.x*256 + threadIdx.x; e < NC*FPIX; e += gridDim.x*256){
        float re = base[(long)e*2], im = base[(long)e*2 + 1];
        s += re*re + im*im;
    }
    red[threadIdx.x] = s; __syncthreads();
    for (int st = 128; st > 0; st >>= 1){
        if (threadIdx.x < st) red[threadIdx.x] += red[threadIdx.x + st];
        __syncthreads();
    }
    if (threadIdx.x == 0) atomicAdd(&dst[bt], red[0]);
}

// ---------------- time recurrence h[t] = A*h[t-1] + X[t] ----------------
__global__ void k_scan(const float* __restrict__ Xf, const float* __restrict__ Abuf,
                       float* __restrict__ Hf){
    int idx = blockIdx.x*256 + threadIdx.x;
    int f = idx % FPIX; int tmp = idx / FPIX;
    int c = tmp % NC; int b = tmp / NC;
    long ao = (((long)(b*NC + c))*FPIX + f)*2;
    float ar = Abuf[ao], ai = Abuf[ao+1];
    float hr = 0.0f, hi = 0.0f;
    for (int t = 0; t < NT; t++){
        long e = (((((long)b*NT + t)*NC + c)*FPIX) + f)*2;
        float xr = Xf[e], xi = Xf[e+1];
        float nr = ar*hr - ai*hi + xr;
        float ni = ar*hi + ai*hr + xi;
        hr = nr; hi = ni;
        Hf[e] = hr; Hf[e+1] = hi;
    }
}

extern "C" void kernel_launch(void* const* d_in, const int* in_sizes, int n_in,
                              void* d_out, int out_size, void* d_ws, size_t ws_size,
                              hipStream_t stream){
    const float* x   = (const float*)d_in[0];
    const float* dt  = (const float*)d_in[1];
    const float* w1  = (const float*)d_in[2];
    const float* b1  = (const float*)d_in[3];
    const float* w2  = (const float*)d_in[4];
    const float* b2  = (const float*)d_in[5];
    const float* c1w = (const float*)d_in[6];
    const float* c1b = (const float*)d_in[7];
    const float* c2w = (const float*)d_in[8];
    const float* c2b = (const float*)d_in[9];
    const float* c3w = (const float*)d_in[10];
    float* out = (float*)d_out;
    float* ws  = (float*)d_ws;

    const long RSZ = (long)NPLANE*FPIX*2;
    float* R1  = ws;
    float* R2  = ws + RSZ;
    float* AB  = R2 + RSZ;
    float* TW  = AB + (long)NB*NC*FPIX*2;
    float* NRM = TW + 384;

    k_tab<<<2, 128, 0, stream>>>(TW, NRM);
    k_A<<<(FPIX + 255)/256, 256, 0, stream>>>(dt, w1, b1, w2, b2, AB);

    for (int ch = 0; ch < NIMG/CHUNK; ch++){
        int img0 = ch*CHUNK;
        float* ys1 = R2;
        float* dy1 = R2 + (long)CHUNK*NC2*PIX;
        float* g2  = R1;
        float* g1  = R2;
        int nb = CHUNK*144;
        k_conv1_t  <<<nb, 256, 0, stream>>>(x, c1w, c1b, ys1, dy1, img0);
        k_conv2g2_t<<<nb, 256, 0, stream>>>(ys1, c2w, c2b, c3w, g2);
        k_g1_t     <<<nb, 256, 0, stream>>>(g2, dy1, c2w, g1);
        k_xp_t     <<<nb, 256, 0, stream>>>(x, g1, c1w, dt, out, img0);
    }

    k_rowfft2<<<NPLANE*12, 192, 0, stream>>>(out, TW, R1);
    k_cfft<-1,false><<<NPLANE*NG, 192, 0, stream>>>(R1, TW, NRM, R2);
    k_constrain<<<NIMG*FPIX/256, 256, 0, stream>>>(R2);
    k_norm<<<dim3(128, NIMG), 256, 0, stream>>>(R2, NRM);
    k_scan<<<NB*NC*FPIX/256, 256, 0, stream>>>(R2, AB, R1);
    k_constrain<<<NIMG*FPIX/256, 256, 0, stream>>>(R1);
    k_norm<<<dim3(128, NIMG), 256, 0, stream>>>(R1, NRM + NIMG);
    k_cfft<+1,true><<<NPLANE*NG, 192, 0, stream>>>(R1, TW, NRM, R2);
    k_invrow2<<<NPLANE*12, 192, 0, stream>>>(R2, TW, out);
}

// Round 5
// 1133.266 us; speedup vs baseline: 8.1468x; 1.5567x over previous
//
#include <hip/hip_runtime.h>
#include <math.h>

#define HH 192
#define WW 192
#define WF 97
#define NC 8
#define NC2 16
#define NT 32
#define NB 2
#define NIMG (NB*NT)        // 64
#define NPLANE (NIMG*NC)    // 512
#define PIX (HH*WW)         // 36864
#define FPIX (HH*WF)        // 18624
#define CHUNK 16            // images per conv chunk
#define NG 13               // column groups of 8 (8*12+1 = 97)
#define INV_SQRT_N 0.07216878364870322f   // 1/sqrt(192)

typedef __attribute__((ext_vector_type(8))) short bf16x8;
typedef __attribute__((ext_vector_type(4))) float f32x4;

__device__ inline unsigned short f2bf(float f){
    unsigned int u = __float_as_uint(f);
    unsigned int r = u + 0x7FFF + ((u >> 16) & 1);
    return (unsigned short)(r >> 16);
}
__device__ inline float bf2f(unsigned short h){
    return __uint_as_float(((unsigned int)h) << 16);
}

// ---------------- tables + norm zero ----------------
__global__ void k_tab(float* tw, float* nrm){
    int i = blockIdx.x*blockDim.x + threadIdx.x;
    if (i < 192){
        double ang = 6.283185307179586476925286766559 * (double)i / 192.0;
        tw[i]       = (float)cos(ang);
        tw[192 + i] = (float)sin(ang);
    }
    if (i < 128) nrm[i] = 0.0f;
}

// ---------------- A = exp(i*omega*dt) via MLP ----------------
__global__ void k_A(const float* __restrict__ dt, const float* __restrict__ w1,
                    const float* __restrict__ b1, const float* __restrict__ w2,
                    const float* __restrict__ b2, float* __restrict__ Abuf){
    int idx = blockIdx.x*blockDim.x + threadIdx.x;
    if (idx >= FPIX) return;
    int i = idx / WF, j = idx % WF;
    float ky = (float)(i < 96 ? i : i - 192) / 192.0f;
    float kx = (float)j / 192.0f;
    float lp[NC];
    #pragma unroll
    for (int c = 0; c < NC; c++) lp[c] = b2[c];
    for (int jh = 0; jh < 64; jh++){
        float z  = ky*w1[jh] + kx*w1[64+jh] + b1[jh];
        float sg = 1.0f/(1.0f + expf(-z));
        float h  = z*sg;
        #pragma unroll
        for (int c = 0; c < NC; c++) lp[c] += h * w2[jh*NC + c];
    }
    float kph = sqrtf(ky*ky + kx*kx);
    for (int b = 0; b < NB; b++){
        float d = dt[b];
        #pragma unroll
        for (int c = 0; c < NC; c++){
            float ph = (lp[c] + kph) * d;
            float s, cn;
            sincosf(ph, &s, &cn);
            long o = (((long)(b*NC + c))*FPIX + idx) * 2;
            Abuf[o]   = cn;
            Abuf[o+1] = s;
        }
    }
}

// =================== MFMA bf16 implicit-GEMM convolutions ===================
// LDS tile: channel-last bf16, 324 halo pixels (18x18) x 16 ch, pixel stride
// 32B so a B-fragment (8 consecutive channels) is one aligned ds_read_b128.
// MFMA 16x16x32: A row = lane&15 (out-ch), B col = lane&15 (pixel),
// k = (lane>>4)*8 + j;  C/D: col = lane&15, row = (lane>>4)*4 + reg.

// stage channel-last bf16 global -> LDS (zero-padded halo)
__device__ inline void stage_cl(const unsigned short* __restrict__ g,
                                unsigned short* lds, int ty0, int tx0, int tid){
    for (int pidx = tid; pidx < 324; pidx += 256){
        int iy = pidx/18, ix = pidx%18;
        int gy = ty0 + iy - 1, gx = tx0 + ix - 1;
        uint4 a = {0,0,0,0}, b = {0,0,0,0};
        if (gy >= 0 && gy < HH && gx >= 0 && gx < WW){
            const uint4* src = (const uint4*)(g + ((long)gy*WW + gx)*16);
            a = src[0]; b = src[1];
        }
        uint4* d = (uint4*)(lds + pidx*16);
        d[0] = a; d[1] = b;
    }
}

// ---- conv1: x(f32 ch-first, 8ch) -> ys1, dy1 (bf16 ch-last, 16ch) ----
// K = 4 taps x 8 ch per MFMA; 3 steps cover 9 taps (+3 zero-weight dummies).
__global__ void k_conv1_m(const float* __restrict__ x, const float* __restrict__ c1w,
                          const float* __restrict__ c1b,
                          unsigned short* __restrict__ ys1,
                          unsigned short* __restrict__ dy1, int img0){
    __shared__ unsigned short lds[324*16];
    int bid = blockIdx.x;
    int tx0 = (bid % 12)*16, ty0 = ((bid/12) % 12)*16;
    int il = bid / 144;
    int img = img0 + il;
    int tid = threadIdx.x;
    int l = tid & 63, px = l & 15, ks = l >> 4, wv = tid >> 6;

    // weights: A[s][row=och=l&15][k=ks*8+j], semantic tap=4s+ks, ch=j
    bf16x8 a[3];
    #pragma unroll
    for (int s = 0; s < 3; s++){
        int tap = 4*s + ks;
        #pragma unroll
        for (int j = 0; j < 8; j++){
            float w = (tap < 9) ? c1w[((px)*8 + j)*9 + tap] : 0.f;  // och = l&15 -> px var reused
            a[s][j] = (short)f2bf(w);
        }
    }
    // stage x tile: 8ch x 18x18 f32 -> bf16 ch-last (ch 8-15 garbage, unread)
    const float* xb = x + (long)img*NC*PIX;
    for (int idx = tid; idx < 2592; idx += 256){
        int c = idx / 324, r = idx % 324;
        int iy = r/18, ix = r%18;
        int gy = ty0 + iy - 1, gx = tx0 + ix - 1;
        float v = 0.f;
        if (gy >= 0 && gy < HH && gx >= 0 && gx < WW) v = xb[c*PIX + gy*WW + gx];
        lds[r*16 + c] = f2bf(v);
    }
    __syncthreads();

    #pragma unroll
    for (int ry = 0; ry < 4; ry++){
        int y = wv*4 + ry;
        f32x4 acc = {0.f,0.f,0.f,0.f};
        #pragma unroll
        for (int s = 0; s < 3; s++){
            int tap = 4*s + ks; int t = (tap < 9) ? tap : 8;
            int dy = t/3, dx = t%3;
            int pix = (y+dy)*18 + (px+dx);
            bf16x8 b = *((const bf16x8*)(lds + pix*16));
            acc = __builtin_amdgcn_mfma_f32_16x16x32_bf16(a[s], b, acc, 0, 0, 0);
        }
        int gpix = (ty0+y)*WW + (tx0+px);
        long base = ((long)il*PIX + gpix)*16 + ks*4;
        ushort4 yo, dyo;
        #pragma unroll
        for (int r = 0; r < 4; r++){
            int och = ks*4 + r;
            float yv = acc[r] + c1b[och];
            float sg = 1.f/(1.f + expf(-yv));
            ((unsigned short*)&yo)[r]  = f2bf(yv*sg);
            ((unsigned short*)&dyo)[r] = f2bf(sg*(1.f + yv*(1.f - sg)));
        }
        *(ushort4*)(ys1 + base) = yo;
        *(ushort4*)(dy1 + base) = dyo;
    }
}

// ---- conv2 + g2 = silu'(y2)*s3 : ys1(16ch) -> g2 (bf16 ch-last) ----
// K = 2 taps x 16 ch per MFMA; 5 steps cover 9 taps (+1 zero-weight dummy).
__global__ void k_conv2_m(const unsigned short* __restrict__ ys1,
                          const float* __restrict__ c2w, const float* __restrict__ c2b,
                          const float* __restrict__ c3w,
                          unsigned short* __restrict__ g2){
    __shared__ unsigned short lds[324*16];
    int bid = blockIdx.x;
    int tx0 = (bid % 12)*16, ty0 = ((bid/12) % 12)*16;
    int il = bid / 144;
    int tid = threadIdx.x;
    int l = tid & 63, px = l & 15, ks = l >> 4, wv = tid >> 6;

    bf16x8 a[5];
    #pragma unroll
    for (int s = 0; s < 5; s++){
        int tap = 2*s + (ks>>1);
        #pragma unroll
        for (int j = 0; j < 8; j++){
            int ch = (ks&1)*8 + j;
            float w = (tap < 9) ? c2w[((px)*16 + ch)*9 + tap] : 0.f;
            a[s][j] = (short)f2bf(w);
        }
    }
    stage_cl(ys1 + (long)il*PIX*16, lds, ty0, tx0, tid);
    __syncthreads();

    #pragma unroll
    for (int ry = 0; ry < 4; ry++){
        int y = wv*4 + ry;
        f32x4 acc = {0.f,0.f,0.f,0.f};
        #pragma unroll
        for (int s = 0; s < 5; s++){
            int tap = 2*s + (ks>>1); int t = (tap < 9) ? tap : 8;
            int dy = t/3, dx = t%3;
            int pix = (y+dy)*18 + (px+dx);
            bf16x8 b = *((const bf16x8*)(lds + pix*16 + (ks&1)*8));
            acc = __builtin_amdgcn_mfma_f32_16x16x32_bf16(a[s], b, acc, 0, 0, 0);
        }
        int gpix = (ty0+y)*WW + (tx0+px);
        long base = ((long)il*PIX + gpix)*16 + ks*4;
        ushort4 go;
        #pragma unroll
        for (int r = 0; r < 4; r++){
            int och = ks*4 + r;
            float yv = acc[r] + c2b[och];
            float sg = 1.f/(1.f + expf(-yv));
            float ds = sg*(1.f + yv*(1.f - sg));
            float s3 = 0.f;
            #pragma unroll
            for (int q = 0; q < NC; q++) s3 += c3w[q*NC2 + och];
            ((unsigned short*)&go)[r] = f2bf(ds * s3);
        }
        *(ushort4*)(g2 + base) = go;
    }
}

// ---- g1 = dy1 * conv2^T(g2): weight tap = 8 - tb (flipped) ----
__global__ void k_g1_m(const unsigned short* __restrict__ g2,
                       const unsigned short* __restrict__ dy1,
                       const float* __restrict__ c2w,
                       unsigned short* __restrict__ g1){
    __shared__ unsigned short lds[324*16];
    int bid = blockIdx.x;
    int tx0 = (bid % 12)*16, ty0 = ((bid/12) % 12)*16;
    int il = bid / 144;
    int tid = threadIdx.x;
    int l = tid & 63, px = l & 15, ks = l >> 4, wv = tid >> 6;

    bf16x8 a[5];
    #pragma unroll
    for (int s = 0; s < 5; s++){
        int tb = 2*s + (ks>>1);
        #pragma unroll
        for (int j = 0; j < 8; j++){
            int c2 = (ks&1)*8 + j;               // input channel (c2)
            float w = (tb < 9) ? c2w[(c2*16 + px)*9 + (8 - tb)] : 0.f;  // out=c1=l&15
            a[s][j] = (short)f2bf(w);
        }
    }
    stage_cl(g2 + (long)il*PIX*16, lds, ty0, tx0, tid);
    __syncthreads();

    #pragma unroll
    for (int ry = 0; ry < 4; ry++){
        int y = wv*4 + ry;
        f32x4 acc = {0.f,0.f,0.f,0.f};
        #pragma unroll
        for (int s = 0; s < 5; s++){
            int tb = 2*s + (ks>>1); int t = (tb < 9) ? tb : 8;
            int dy = t/3, dx = t%3;
            int pix = (y+dy)*18 + (px+dx);
            bf16x8 b = *((const bf16x8*)(lds + pix*16 + (ks&1)*8));
            acc = __builtin_amdgcn_mfma_f32_16x16x32_bf16(a[s], b, acc, 0, 0, 0);
        }
        int gpix = (ty0+y)*WW + (tx0+px);
        long base = ((long)il*PIX + gpix)*16 + ks*4;
        ushort4 dv = *(const ushort4*)(dy1 + base);
        ushort4 go;
        #pragma unroll
        for (int r = 0; r < 4; r++){
            float v = acc[r] * bf2f(((unsigned short*)&dv)[r]);
            ((unsigned short*)&go)[r] = f2bf(v);
        }
        *(ushort4*)(g1 + base) = go;
    }
}

// ---- xp = x + dt * conv1^T(g1): out 8 ch (rows 8-15 zero-weight waste) ----
__global__ void k_xp_m(const float* __restrict__ x,
                       const unsigned short* __restrict__ g1,
                       const float* __restrict__ c1w, const float* __restrict__ dt,
                       float* __restrict__ xp, int img0){
    __shared__ unsigned short lds[324*16];
    int bid = blockIdx.x;
    int tx0 = (bid % 12)*16, ty0 = ((bid/12) % 12)*16;
    int il = bid / 144;
    int img = img0 + il;
    int tid = threadIdx.x;
    int l = tid & 63, px = l & 15, ks = l >> 4, wv = tid >> 6;

    bf16x8 a[5];
    #pragma unroll
    for (int s = 0; s < 5; s++){
        int tb = 2*s + (ks>>1);
        #pragma unroll
        for (int j = 0; j < 8; j++){
            int cin = (ks&1)*8 + j;              // input channel (o of conv1)
            float w = (tb < 9 && px < 8) ? c1w[(cin*8 + px)*9 + (8 - tb)] : 0.f;
            a[s][j] = (short)f2bf(w);
        }
    }
    stage_cl(g1 + (long)il*PIX*16, lds, ty0, tx0, tid);
    __syncthreads();

    float d = dt[img / NT];
    #pragma unroll
    for (int ry = 0; ry < 4; ry++){
        int y = wv*4 + ry;
        f32x4 acc = {0.f,0.f,0.f,0.f};
        #pragma unroll
        for (int s = 0; s < 5; s++){
            int tb = 2*s + (ks>>1); int t = (tb < 9) ? tb : 8;
            int dy = t/3, dx = t%3;
            int pix = (y+dy)*18 + (px+dx);
            bf16x8 b = *((const bf16x8*)(lds + pix*16 + (ks&1)*8));
            acc = __builtin_amdgcn_mfma_f32_16x16x32_bf16(a[s], b, acc, 0, 0, 0);
        }
        if (ks < 2){
            int gpix = (ty0+y)*WW + (tx0+px);
            #pragma unroll
            for (int r = 0; r < 4; r++){
                int c = ks*4 + r;
                long gi = ((long)img*NC + c)*PIX + gpix;
                xp[gi] = x[gi] + d*acc[r];
            }
        }
    }
}

// ====== two-stage row rfft (192=16x12), 2 real rows packed per complex =====
__global__ void k_rowfft2(const float* __restrict__ xp, const float* __restrict__ tw,
                          float* __restrict__ R){
    __shared__ float2 C[192][9];       // input z / reused for Z
    __shared__ float2 A1[12][16][9];   // stage-1 result [n2][k1][jj]
    __shared__ float twc[192], tws[192];
    int p  = blockIdx.x / 12;
    int r0 = (blockIdx.x % 12)*16;
    int t  = threadIdx.x;
    twc[t] = tw[t]; tws[t] = tw[192+t];
    const float* base = xp + (long)p*PIX + (long)r0*WW;
    #pragma unroll
    for (int jj = 0; jj < 8; jj++){
        float2 z; z.x = base[(2*jj)*WW + t]; z.y = base[(2*jj+1)*WW + t];
        C[t][jj] = z;
    }
    __syncthreads();
    {   // stage 1
        int k1 = t / 12, n2 = t % 12;
        float wr[16], wi[16];
        int m = n2*k1 % 192, step = (12*k1) % 192;
        #pragma unroll
        for (int n1 = 0; n1 < 16; n1++){
            wr[n1] = twc[m]; wi[n1] = -tws[m];
            m += step; if (m >= 192) m -= 192;
        }
        #pragma unroll
        for (int jj = 0; jj < 8; jj++){
            float re = 0.f, im = 0.f;
            #pragma unroll
            for (int n1 = 0; n1 < 16; n1++){
                float2 v = C[12*n1 + n2][jj];
                re += v.x*wr[n1] - v.y*wi[n1];
                im += v.x*wi[n1] + v.y*wr[n1];
            }
            float2 a; a.x = re; a.y = im;
            A1[n2][k1][jj] = a;
        }
    }
    __syncthreads();
    {   // stage 2
        int k1 = t % 16, k2 = t / 16;
        float wr[12], wi[12];
        int m = 0, step = (16*k2) % 192;
        #pragma unroll
        for (int n2 = 0; n2 < 12; n2++){
            wr[n2] = twc[m]; wi[n2] = -tws[m];
            m += step; if (m >= 192) m -= 192;
        }
        #pragma unroll
        for (int jj = 0; jj < 8; jj++){
            float re = 0.f, im = 0.f;
            #pragma unroll
            for (int n2 = 0; n2 < 12; n2++){
                float2 a = A1[n2][k1][jj];
                re += a.x*wr[n2] - a.y*wi[n2];
                im += a.x*wi[n2] + a.y*wr[n2];
            }
            float2 z; z.x = re*INV_SQRT_N; z.y = im*INV_SQRT_N;
            C[t][jj] = z;
        }
    }
    __syncthreads();
    if (t < WF){                           // Hermitian unpack
        int t2 = (t == 0) ? 0 : 192 - t;
        float2* dst = ((float2*)R) + ((long)p*HH + r0)*WF + t;
        #pragma unroll
        for (int jj = 0; jj < 8; jj++){
            float2 u = C[t][jj], v = C[t2][jj];
            float2 A_; A_.x = 0.5f*(u.x + v.x); A_.y = 0.5f*(u.y - v.y);
            float2 B_; B_.x = 0.5f*(u.y + v.y); B_.y = -0.5f*(u.x - v.x);
            dst[(2*jj)*WF]   = A_;
            dst[(2*jj+1)*WF] = B_;
        }
    }
}

// ====== two-stage inverse row irfft, 2 spectra packed per complex ifft =====
// C2R convention: Im of DC (kx=0) and Nyquist (kx=96) bins ignored (zeroed).
__global__ void k_invrow2(const float* __restrict__ G, const float* __restrict__ tw,
                          float* __restrict__ out){
    __shared__ float2 C[192][9];
    __shared__ float2 A1[12][16][9];
    __shared__ float twc[192], tws[192];
    int p  = blockIdx.x / 12;
    int r0 = (blockIdx.x % 12)*16;
    int t  = threadIdx.x;
    twc[t] = tw[t]; tws[t] = tw[192+t];
    const float2* Gb = ((const float2*)G) + ((long)p*HH + r0)*WF;
    int tt = (t <= 96) ? t : 192 - t;
    bool dcny = (t == 0) || (t == 96);
    #pragma unroll
    for (int jj = 0; jj < 8; jj++){
        float2 a = Gb[(2*jj)*WF + tt];
        float2 b = Gb[(2*jj+1)*WF + tt];
        if (dcny){ a.y = 0.f; b.y = 0.f; }
        float2 z;
        if (t <= 96){ z.x = a.x - b.y; z.y = a.y + b.x; }
        else        { z.x = a.x + b.y; z.y = b.x - a.y; }
        C[t][jj] = z;
    }
    __syncthreads();
    {   // stage 1 (e^{+i})
        int k1 = t / 12, n2 = t % 12;
        float wr[16], wi[16];
        int m = n2*k1 % 192, step = (12*k1) % 192;
        #pragma unroll
        for (int n1 = 0; n1 < 16; n1++){
            wr[n1] = twc[m]; wi[n1] = tws[m];
            m += step; if (m >= 192) m -= 192;
        }
        #pragma unroll
        for (int jj = 0; jj < 8; jj++){
            float re = 0.f, im = 0.f;
            #pragma unroll
            for (int n1 = 0; n1 < 16; n1++){
                float2 v = C[12*n1 + n2][jj];
                re += v.x*wr[n1] - v.y*wi[n1];
                im += v.x*wi[n1] + v.y*wr[n1];
            }
            float2 a; a.x = re; a.y = im;
            A1[n2][k1][jj] = a;
        }
    }
    __syncthreads();
    {   // stage 2 (e^{+i}): Re->rowA, Im->rowB
        int k1 = t % 16, k2 = t / 16;
        float wr[12], wi[12];
        int m = 0, step = (16*k2) % 192;
        #pragma unroll
        for (int n2 = 0; n2 < 12; n2++){
            wr[n2] = twc[m]; wi[n2] = tws[m];
            m += step; if (m >= 192) m -= 192;
        }
        float* ob = out + (long)p*PIX + (long)r0*WW;
        #pragma unroll
        for (int jj = 0; jj < 8; jj++){
            float re = 0.f, im = 0.f;
            #pragma unroll
            for (int n2 = 0; n2 < 12; n2++){
                float2 a = A1[n2][k1][jj];
                re += a.x*wr[n2] - a.y*wi[n2];
                im += a.x*wi[n2] + a.y*wr[n2];
            }
            ob[(2*jj)*WW + t]   = re*INV_SQRT_N;
            ob[(2*jj+1)*WW + t] = im*INV_SQRT_N;
        }
    }
}

// ========== two-stage column FFT: 192 = 16 x 12, 8 columns per block =======
template<int DIRSGN, bool RESCALE>
__global__ void k_cfft(const float* __restrict__ in, const float* __restrict__ tw,
                       const float* __restrict__ nrm, float* __restrict__ out){
    __shared__ float2 C[HH][9];
    __shared__ float2 A1[12][16][9];   // [n2][k1][jj]
    __shared__ float twc[192], tws[192];
    const float sgn = (DIRSGN > 0) ? 1.f : -1.f;
    int p  = blockIdx.x / NG;
    int g  = blockIdx.x % NG;
    int j0 = g*8;
    int t  = threadIdx.x;
    twc[t] = tw[t]; tws[t] = tw[192+t];
    float scale = 1.f;
    if (RESCALE){
        int bt = p / NC;
        scale = sqrtf(nrm[bt]) / (sqrtf(nrm[64+bt]) + 1e-6f);
    }
    const float2* src = ((const float2*)in) + ((long)p*HH + t)*WF + j0;
    #pragma unroll
    for (int jj = 0; jj < 8; jj++){
        float2 v = {0.f, 0.f};
        if (j0 + jj < WF) v = src[jj];
        v.x *= scale; v.y *= scale;
        C[t][jj] = v;
    }
    __syncthreads();
    {   // stage 1
        int k1 = t / 12, n2 = t % 12;
        float wr[16], wi[16];
        int m = n2*k1 % 192, step = (12*k1) % 192;
        #pragma unroll
        for (int n1 = 0; n1 < 16; n1++){
            wr[n1] = twc[m]; wi[n1] = sgn*tws[m];
            m += step; if (m >= 192) m -= 192;
        }
        #pragma unroll
        for (int jj = 0; jj < 8; jj++){
            float re = 0.f, im = 0.f;
            #pragma unroll
            for (int n1 = 0; n1 < 16; n1++){
                float2 v = C[12*n1 + n2][jj];
                re += v.x*wr[n1] - v.y*wi[n1];
                im += v.x*wi[n1] + v.y*wr[n1];
            }
            float2 a; a.x = re; a.y = im;
            A1[n2][k1][jj] = a;
        }
    }
    __syncthreads();
    {   // stage 2: ky == t
        int k1 = t % 16, k2 = t / 16;
        float wr[12], wi[12];
        int m = 0, step = (16*k2) % 192;
        #pragma unroll
        for (int n2 = 0; n2 < 12; n2++){
            wr[n2] = twc[m]; wi[n2] = sgn*tws[m];
            m += step; if (m >= 192) m -= 192;
        }
        float2* dst = ((float2*)out) + ((long)p*HH + t)*WF + j0;
        #pragma unroll
        for (int jj = 0; jj < 8; jj++){
            float re = 0.f, im = 0.f;
            #pragma unroll
            for (int n2 = 0; n2 < 12; n2++){
                float2 a = A1[n2][k1][jj];
                re += a.x*wr[n2] - a.y*wi[n2];
                im += a.x*wi[n2] + a.y*wr[n2];
            }
            if (j0 + jj < WF){
                float2 r; r.x = re*INV_SQRT_N; r.y = im*INV_SQRT_N;
                dst[jj] = r;
            }
        }
    }
}

// ---------------- divergence projection (channels 0,1) ----------------
__global__ void k_constrain(float* __restrict__ F){
    int idx = blockIdx.x*256 + threadIdx.x;
    int j = idx % WF; int tmp = idx / WF;
    int i = tmp % HH; int bt = tmp / HH;
    float ky = (float)(i < 96 ? i : i - 192)/192.0f;
    float kx = (float)j/192.0f;
    float k2 = ky*ky + kx*kx;
    if (i == 0 && j == 0) k2 = 1.0f;
    long ui = ((((long)bt*NC + 0)*HH + i)*WF + j)*2;
    long vi = ((((long)bt*NC + 1)*HH + i)*WF + j)*2;
    float ur = F[ui], um = F[ui+1], vr = F[vi], vm = F[vi+1];
    float dr = (ky*ur + kx*vr)/k2;
    float di = (ky*um + kx*vm)/k2;
    F[ui]   = ur - ky*dr;  F[ui+1] = um - ky*di;
    F[vi]   = vr - kx*dr;  F[vi+1] = vm - kx*di;
}

// ---------------- per-(b,t) energy reduction ----------------
__global__ void k_norm(const float* __restrict__ F, float* __restrict__ dst){
    int bt = blockIdx.y;
    __shared__ float red[256];
    float s = 0.0f;
    const float* base = F + (long)bt*NC*FPIX*2;
    for (int e = blockIdx.x*256 + threadIdx.x; e < NC*FPIX; e += gridDim.x*256){
        float re = base[(long)e*2], im = base[(long)e*2 + 1];
        s += re*re + im*im;
    }
    red[threadIdx.x] = s; __syncthreads();
    for (int st = 128; st > 0; st >>= 1){
        if (threadIdx.x < st) red[threadIdx.x] += red[threadIdx.x + st];
        __syncthreads();
    }
    if (threadIdx.x == 0) atomicAdd(&dst[bt], red[0]);
}

// ---------------- time recurrence h[t] = A*h[t-1] + X[t] ----------------
__global__ void k_scan(const float* __restrict__ Xf, const float* __restrict__ Abuf,
                       float* __restrict__ Hf){
    int idx = blockIdx.x*256 + threadIdx.x;
    int f = idx % FPIX; int tmp = idx / FPIX;
    int c = tmp % NC; int b = tmp / NC;
    long ao = (((long)(b*NC + c))*FPIX + f)*2;
    float ar = Abuf[ao], ai = Abuf[ao+1];
    float hr = 0.0f, hi = 0.0f;
    for (int t = 0; t < NT; t++){
        long e = (((((long)b*NT + t)*NC + c)*FPIX) + f)*2;
        float xr = Xf[e], xi = Xf[e+1];
        float nr = ar*hr - ai*hi + xr;
        float ni = ar*hi + ai*hr + xi;
        hr = nr; hi = ni;
        Hf[e] = hr; Hf[e+1] = hi;
    }
}

extern "C" void kernel_launch(void* const* d_in, const int* in_sizes, int n_in,
                              void* d_out, int out_size, void* d_ws, size_t ws_size,
                              hipStream_t stream){
    const float* x   = (const float*)d_in[0];
    const float* dt  = (const float*)d_in[1];
    const float* w1  = (const float*)d_in[2];
    const float* b1  = (const float*)d_in[3];
    const float* w2  = (const float*)d_in[4];
    const float* b2  = (const float*)d_in[5];
    const float* c1w = (const float*)d_in[6];
    const float* c1b = (const float*)d_in[7];
    const float* c2w = (const float*)d_in[8];
    const float* c2b = (const float*)d_in[9];
    const float* c3w = (const float*)d_in[10];
    float* out = (float*)d_out;
    float* ws  = (float*)d_ws;

    const long RSZ = (long)NPLANE*FPIX*2;
    float* R1  = ws;
    float* R2  = ws + RSZ;
    float* AB  = R2 + RSZ;
    float* TW  = AB + (long)NB*NC*FPIX*2;
    float* NRM = TW + 384;

    // bf16 channel-last conv intermediates (views into R1/R2)
    unsigned short* ys1 = (unsigned short*)R2;                 // 16 ch
    unsigned short* dy1 = ys1 + (long)CHUNK*PIX*16;            // 16 ch
    unsigned short* g2b = (unsigned short*)R1;                 // 16 ch
    unsigned short* g1b = (unsigned short*)R2;                 // overwrites ys1

    k_tab<<<2, 128, 0, stream>>>(TW, NRM);
    k_A<<<(FPIX + 255)/256, 256, 0, stream>>>(dt, w1, b1, w2, b2, AB);

    for (int ch = 0; ch < NIMG/CHUNK; ch++){
        int img0 = ch*CHUNK;
        int nb = CHUNK*144;
        k_conv1_m<<<nb, 256, 0, stream>>>(x, c1w, c1b, ys1, dy1, img0);
        k_conv2_m<<<nb, 256, 0, stream>>>(ys1, c2w, c2b, c3w, g2b);
        k_g1_m   <<<nb, 256, 0, stream>>>(g2b, dy1, c2w, g1b);
        k_xp_m   <<<nb, 256, 0, stream>>>(x, g1b, c1w, dt, out, img0);
    }

    k_rowfft2<<<NPLANE*12, 192, 0, stream>>>(out, TW, R1);
    k_cfft<-1,false><<<NPLANE*NG, 192, 0, stream>>>(R1, TW, NRM, R2);
    k_constrain<<<NIMG*FPIX/256, 256, 0, stream>>>(R2);
    k_norm<<<dim3(128, NIMG), 256, 0, stream>>>(R2, NRM);
    k_scan<<<NB*NC*FPIX/256, 256, 0, stream>>>(R2, AB, R1);
    k_constrain<<<NIMG*FPIX/256, 256, 0, stream>>>(R1);
    k_norm<<<dim3(128, NIMG), 256, 0, stream>>>(R1, NRM + NIMG);
    k_cfft<+1,true><<<NPLANE*NG, 192, 0, stream>>>(R1, TW, NRM, R2);
    k_invrow2<<<NPLANE*12, 192, 0, stream>>>(R2, TW, out);
}

// Round 6
// 1094.726 us; speedup vs baseline: 8.4336x; 1.0352x over previous
//
#include <hip/hip_runtime.h>
#include <math.h>

#define HH 192
#define WW 192
#define WF 97
#define NC 8
#define NC2 16
#define NT 32
#define NB 2
#define NIMG (NB*NT)        // 64
#define NPLANE (NIMG*NC)    // 512
#define PIX (HH*WW)         // 36864
#define FPIX (HH*WF)        // 18624  (layout: [plane][kx][ky], f = kx*192+ky)
#define CHUNK 16            // images per conv chunk
#define NG 13               // kx groups of 8 (8*12+1 = 97)
#define INV_SQRT_N 0.07216878364870322f   // 1/sqrt(192)

typedef __attribute__((ext_vector_type(8))) short bf16x8;
typedef __attribute__((ext_vector_type(4))) float f32x4;

__device__ inline unsigned short f2bf(float f){
    unsigned int u = __float_as_uint(f);
    unsigned int r = u + 0x7FFF + ((u >> 16) & 1);
    return (unsigned short)(r >> 16);
}
__device__ inline float bf2f(unsigned short h){
    return __uint_as_float(((unsigned int)h) << 16);
}

// ---------------- tables + norm zero ----------------
__global__ void k_tab(float* tw, float* nrm){
    int i = blockIdx.x*blockDim.x + threadIdx.x;
    if (i < 192){
        double ang = 6.283185307179586476925286766559 * (double)i / 192.0;
        tw[i]       = (float)cos(ang);
        tw[192 + i] = (float)sin(ang);
    }
    if (i < 128) nrm[i] = 0.0f;
}

// ---------------- A = exp(i*omega*dt) via MLP (f = kx*192+ky) ----------------
__global__ void k_A(const float* __restrict__ dt, const float* __restrict__ w1,
                    const float* __restrict__ b1, const float* __restrict__ w2,
                    const float* __restrict__ b2, float* __restrict__ Abuf){
    int idx = blockIdx.x*blockDim.x + threadIdx.x;
    if (idx >= FPIX) return;
    int kyi = idx % HH, kxi = idx / HH;
    float ky = (float)(kyi < 96 ? kyi : kyi - 192) / 192.0f;
    float kx = (float)kxi / 192.0f;
    float lp[NC];
    #pragma unroll
    for (int c = 0; c < NC; c++) lp[c] = b2[c];
    for (int jh = 0; jh < 64; jh++){
        float z  = ky*w1[jh] + kx*w1[64+jh] + b1[jh];
        float sg = 1.0f/(1.0f + expf(-z));
        float h  = z*sg;
        #pragma unroll
        for (int c = 0; c < NC; c++) lp[c] += h * w2[jh*NC + c];
    }
    float kph = sqrtf(ky*ky + kx*kx);
    for (int b = 0; b < NB; b++){
        float d = dt[b];
        #pragma unroll
        for (int c = 0; c < NC; c++){
            float ph = (lp[c] + kph) * d;
            float s, cn;
            sincosf(ph, &s, &cn);
            long o = (((long)(b*NC + c))*FPIX + idx) * 2;
            Abuf[o]   = cn;
            Abuf[o+1] = s;
        }
    }
}

// =================== MFMA bf16 implicit-GEMM convolutions ===================
__device__ inline void stage_cl(const unsigned short* __restrict__ g,
                                unsigned short* lds, int ty0, int tx0, int tid){
    for (int pidx = tid; pidx < 324; pidx += 256){
        int iy = pidx/18, ix = pidx%18;
        int gy = ty0 + iy - 1, gx = tx0 + ix - 1;
        uint4 a = {0,0,0,0}, b = {0,0,0,0};
        if (gy >= 0 && gy < HH && gx >= 0 && gx < WW){
            const uint4* src = (const uint4*)(g + ((long)gy*WW + gx)*16);
            a = src[0]; b = src[1];
        }
        uint4* d = (uint4*)(lds + pidx*16);
        d[0] = a; d[1] = b;
    }
}

__global__ void k_conv1_m(const float* __restrict__ x, const float* __restrict__ c1w,
                          const float* __restrict__ c1b,
                          unsigned short* __restrict__ ys1,
                          unsigned short* __restrict__ dy1, int img0){
    __shared__ unsigned short lds[324*16];
    int bid = blockIdx.x;
    int tx0 = (bid % 12)*16, ty0 = ((bid/12) % 12)*16;
    int il = bid / 144;
    int img = img0 + il;
    int tid = threadIdx.x;
    int l = tid & 63, px = l & 15, ks = l >> 4, wv = tid >> 6;

    bf16x8 a[3];
    #pragma unroll
    for (int s = 0; s < 3; s++){
        int tap = 4*s + ks;
        #pragma unroll
        for (int j = 0; j < 8; j++){
            float w = (tap < 9) ? c1w[((px)*8 + j)*9 + tap] : 0.f;
            a[s][j] = (short)f2bf(w);
        }
    }
    const float* xb = x + (long)img*NC*PIX;
    for (int idx = tid; idx < 2592; idx += 256){
        int c = idx / 324, r = idx % 324;
        int iy = r/18, ix = r%18;
        int gy = ty0 + iy - 1, gx = tx0 + ix - 1;
        float v = 0.f;
        if (gy >= 0 && gy < HH && gx >= 0 && gx < WW) v = xb[c*PIX + gy*WW + gx];
        lds[r*16 + c] = f2bf(v);
    }
    __syncthreads();

    #pragma unroll
    for (int ry = 0; ry < 4; ry++){
        int y = wv*4 + ry;
        f32x4 acc = {0.f,0.f,0.f,0.f};
        #pragma unroll
        for (int s = 0; s < 3; s++){
            int tap = 4*s + ks; int t = (tap < 9) ? tap : 8;
            int dy = t/3, dx = t%3;
            int pix = (y+dy)*18 + (px+dx);
            bf16x8 b = *((const bf16x8*)(lds + pix*16));
            acc = __builtin_amdgcn_mfma_f32_16x16x32_bf16(a[s], b, acc, 0, 0, 0);
        }
        int gpix = (ty0+y)*WW + (tx0+px);
        long base = ((long)il*PIX + gpix)*16 + ks*4;
        ushort4 yo, dyo;
        #pragma unroll
        for (int r = 0; r < 4; r++){
            int och = ks*4 + r;
            float yv = acc[r] + c1b[och];
            float sg = 1.f/(1.f + expf(-yv));
            ((unsigned short*)&yo)[r]  = f2bf(yv*sg);
            ((unsigned short*)&dyo)[r] = f2bf(sg*(1.f + yv*(1.f - sg)));
        }
        *(ushort4*)(ys1 + base) = yo;
        *(ushort4*)(dy1 + base) = dyo;
    }
}

__global__ void k_conv2_m(const unsigned short* __restrict__ ys1,
                          const float* __restrict__ c2w, const float* __restrict__ c2b,
                          const float* __restrict__ c3w,
                          unsigned short* __restrict__ g2){
    __shared__ unsigned short lds[324*16];
    int bid = blockIdx.x;
    int tx0 = (bid % 12)*16, ty0 = ((bid/12) % 12)*16;
    int il = bid / 144;
    int tid = threadIdx.x;
    int l = tid & 63, px = l & 15, ks = l >> 4, wv = tid >> 6;

    bf16x8 a[5];
    #pragma unroll
    for (int s = 0; s < 5; s++){
        int tap = 2*s + (ks>>1);
        #pragma unroll
        for (int j = 0; j < 8; j++){
            int ch = (ks&1)*8 + j;
            float w = (tap < 9) ? c2w[((px)*16 + ch)*9 + tap] : 0.f;
            a[s][j] = (short)f2bf(w);
        }
    }
    stage_cl(ys1 + (long)il*PIX*16, lds, ty0, tx0, tid);
    __syncthreads();

    #pragma unroll
    for (int ry = 0; ry < 4; ry++){
        int y = wv*4 + ry;
        f32x4 acc = {0.f,0.f,0.f,0.f};
        #pragma unroll
        for (int s = 0; s < 5; s++){
            int tap = 2*s + (ks>>1); int t = (tap < 9) ? tap : 8;
            int dy = t/3, dx = t%3;
            int pix = (y+dy)*18 + (px+dx);
            bf16x8 b = *((const bf16x8*)(lds + pix*16 + (ks&1)*8));
            acc = __builtin_amdgcn_mfma_f32_16x16x32_bf16(a[s], b, acc, 0, 0, 0);
        }
        int gpix = (ty0+y)*WW + (tx0+px);
        long base = ((long)il*PIX + gpix)*16 + ks*4;
        ushort4 go;
        #pragma unroll
        for (int r = 0; r < 4; r++){
            int och = ks*4 + r;
            float yv = acc[r] + c2b[och];
            float sg = 1.f/(1.f + expf(-yv));
            float ds = sg*(1.f + yv*(1.f - sg));
            float s3 = 0.f;
            #pragma unroll
            for (int q = 0; q < NC; q++) s3 += c3w[q*NC2 + och];
            ((unsigned short*)&go)[r] = f2bf(ds * s3);
        }
        *(ushort4*)(g2 + base) = go;
    }
}

__global__ void k_g1_m(const unsigned short* __restrict__ g2,
                       const unsigned short* __restrict__ dy1,
                       const float* __restrict__ c2w,
                       unsigned short* __restrict__ g1){
    __shared__ unsigned short lds[324*16];
    int bid = blockIdx.x;
    int tx0 = (bid % 12)*16, ty0 = ((bid/12) % 12)*16;
    int il = bid / 144;
    int tid = threadIdx.x;
    int l = tid & 63, px = l & 15, ks = l >> 4, wv = tid >> 6;

    bf16x8 a[5];
    #pragma unroll
    for (int s = 0; s < 5; s++){
        int tb = 2*s + (ks>>1);
        #pragma unroll
        for (int j = 0; j < 8; j++){
            int c2 = (ks&1)*8 + j;
            float w = (tb < 9) ? c2w[(c2*16 + px)*9 + (8 - tb)] : 0.f;
            a[s][j] = (short)f2bf(w);
        }
    }
    stage_cl(g2 + (long)il*PIX*16, lds, ty0, tx0, tid);
    __syncthreads();

    #pragma unroll
    for (int ry = 0; ry < 4; ry++){
        int y = wv*4 + ry;
        f32x4 acc = {0.f,0.f,0.f,0.f};
        #pragma unroll
        for (int s = 0; s < 5; s++){
            int tb = 2*s + (ks>>1); int t = (tb < 9) ? tb : 8;
            int dy = t/3, dx = t%3;
            int pix = (y+dy)*18 + (px+dx);
            bf16x8 b = *((const bf16x8*)(lds + pix*16 + (ks&1)*8));
            acc = __builtin_amdgcn_mfma_f32_16x16x32_bf16(a[s], b, acc, 0, 0, 0);
        }
        int gpix = (ty0+y)*WW + (tx0+px);
        long base = ((long)il*PIX + gpix)*16 + ks*4;
        ushort4 dv = *(const ushort4*)(dy1 + base);
        ushort4 go;
        #pragma unroll
        for (int r = 0; r < 4; r++){
            float v = acc[r] * bf2f(((unsigned short*)&dv)[r]);
            ((unsigned short*)&go)[r] = f2bf(v);
        }
        *(ushort4*)(g1 + base) = go;
    }
}

__global__ void k_xp_m(const float* __restrict__ x,
                       const unsigned short* __restrict__ g1,
                       const float* __restrict__ c1w, const float* __restrict__ dt,
                       float* __restrict__ xp, int img0){
    __shared__ unsigned short lds[324*16];
    int bid = blockIdx.x;
    int tx0 = (bid % 12)*16, ty0 = ((bid/12) % 12)*16;
    int il = bid / 144;
    int img = img0 + il;
    int tid = threadIdx.x;
    int l = tid & 63, px = l & 15, ks = l >> 4, wv = tid >> 6;

    bf16x8 a[5];
    #pragma unroll
    for (int s = 0; s < 5; s++){
        int tb = 2*s + (ks>>1);
        #pragma unroll
        for (int j = 0; j < 8; j++){
            int cin = (ks&1)*8 + j;
            float w = (tb < 9 && px < 8) ? c1w[(cin*8 + px)*9 + (8 - tb)] : 0.f;
            a[s][j] = (short)f2bf(w);
        }
    }
    stage_cl(g1 + (long)il*PIX*16, lds, ty0, tx0, tid);
    __syncthreads();

    float d = dt[img / NT];
    #pragma unroll
    for (int ry = 0; ry < 4; ry++){
        int y = wv*4 + ry;
        f32x4 acc = {0.f,0.f,0.f,0.f};
        #pragma unroll
        for (int s = 0; s < 5; s++){
            int tb = 2*s + (ks>>1); int t = (tb < 9) ? tb : 8;
            int dy = t/3, dx = t%3;
            int pix = (y+dy)*18 + (px+dx);
            bf16x8 b = *((const bf16x8*)(lds + pix*16 + (ks&1)*8));
            acc = __builtin_amdgcn_mfma_f32_16x16x32_bf16(a[s], b, acc, 0, 0, 0);
        }
        if (ks < 2){
            int gpix = (ty0+y)*WW + (tx0+px);
            #pragma unroll
            for (int r = 0; r < 4; r++){
                int c = ks*4 + r;
                long gi = ((long)img*NC + c)*PIX + gpix;
                xp[gi] = x[gi] + d*acc[r];
            }
        }
    }
}

// ====== row rfft (192=16x12), 2 real rows per complex; out [plane][kx][ky] ==
__global__ void k_rowfft2(const float* __restrict__ xp, const float* __restrict__ tw,
                          float* __restrict__ R){
    __shared__ float2 C[192][9];
    __shared__ float2 A1[12][17][9];   // padded middle dim: bank fix
    __shared__ float2 U[97][17];       // transpose staging
    __shared__ float twc[192], tws[192];
    int p  = blockIdx.x / 12;
    int r0 = (blockIdx.x % 12)*16;
    int t  = threadIdx.x;
    twc[t] = tw[t]; tws[t] = tw[192+t];
    const float* base = xp + (long)p*PIX + (long)r0*WW;
    #pragma unroll
    for (int jj = 0; jj < 8; jj++){
        float2 z; z.x = base[(2*jj)*WW + t]; z.y = base[(2*jj+1)*WW + t];
        C[t][jj] = z;
    }
    __syncthreads();
    {   // stage 1
        int k1 = t / 12, n2 = t % 12;
        float wr[16], wi[16];
        int m = n2*k1 % 192, step = (12*k1) % 192;
        #pragma unroll
        for (int n1 = 0; n1 < 16; n1++){
            wr[n1] = twc[m]; wi[n1] = -tws[m];
            m += step; if (m >= 192) m -= 192;
        }
        #pragma unroll
        for (int jj = 0; jj < 8; jj++){
            float re = 0.f, im = 0.f;
            #pragma unroll
            for (int n1 = 0; n1 < 16; n1++){
                float2 v = C[12*n1 + n2][jj];
                re += v.x*wr[n1] - v.y*wi[n1];
                im += v.x*wi[n1] + v.y*wr[n1];
            }
            float2 a; a.x = re; a.y = im;
            A1[n2][k1][jj] = a;
        }
    }
    __syncthreads();
    {   // stage 2
        int k1 = t % 16, k2 = t / 16;
        float wr[12], wi[12];
        int m = 0, step = (16*k2) % 192;
        #pragma unroll
        for (int n2 = 0; n2 < 12; n2++){
            wr[n2] = twc[m]; wi[n2] = -tws[m];
            m += step; if (m >= 192) m -= 192;
        }
        #pragma unroll
        for (int jj = 0; jj < 8; jj++){
            float re = 0.f, im = 0.f;
            #pragma unroll
            for (int n2 = 0; n2 < 12; n2++){
                float2 a = A1[n2][k1][jj];
                re += a.x*wr[n2] - a.y*wi[n2];
                im += a.x*wi[n2] + a.y*wr[n2];
            }
            float2 z; z.x = re*INV_SQRT_N; z.y = im*INV_SQRT_N;
            C[t][jj] = z;
        }
    }
    __syncthreads();
    if (t < WF){                           // Hermitian unpack -> U[kx][row]
        int t2 = (t == 0) ? 0 : 192 - t;
        #pragma unroll
        for (int jj = 0; jj < 8; jj++){
            float2 u = C[t][jj], v = C[t2][jj];
            float2 A_; A_.x = 0.5f*(u.x + v.x); A_.y = 0.5f*(u.y - v.y);
            float2 B_; B_.x = 0.5f*(u.y + v.y); B_.y = -0.5f*(u.x - v.x);
            U[t][2*jj]   = A_;
            U[t][2*jj+1] = B_;
        }
    }
    __syncthreads();
    float2* dst = ((float2*)R) + (long)p*FPIX + r0;  // + kx*HH + ry
    for (int idx = t; idx < 97*16; idx += 192){
        int kx = idx >> 4, ry = idx & 15;
        dst[(long)kx*HH + ry] = U[kx][ry];
    }
}

// ====== inverse row irfft, in [plane][kx][ky]; 2 spectra per complex ifft ==
// C2R: Im of DC (kx=0) and Nyquist (kx=96) bins zeroed (numpy convention).
__global__ void k_invrow2(const float* __restrict__ G, const float* __restrict__ tw,
                          float* __restrict__ out){
    __shared__ float2 G_s[97][17];
    __shared__ float2 C[192][9];
    __shared__ float2 A1[12][17][9];
    __shared__ float twc[192], tws[192];
    int p  = blockIdx.x / 12;
    int r0 = (blockIdx.x % 12)*16;
    int t  = threadIdx.x;
    twc[t] = tw[t]; tws[t] = tw[192+t];
    const float2* Gb = ((const float2*)G) + (long)p*FPIX + r0;
    for (int idx = t; idx < 97*16; idx += 192){
        int kx = idx >> 4, ry = idx & 15;
        G_s[kx][ry] = Gb[(long)kx*HH + ry];
    }
    __syncthreads();
    int tt = (t <= 96) ? t : 192 - t;
    bool dcny = (t == 0) || (t == 96);
    #pragma unroll
    for (int jj = 0; jj < 8; jj++){
        float2 a = G_s[tt][2*jj];
        float2 b = G_s[tt][2*jj+1];
        if (dcny){ a.y = 0.f; b.y = 0.f; }
        float2 z;
        if (t <= 96){ z.x = a.x - b.y; z.y = a.y + b.x; }
        else        { z.x = a.x + b.y; z.y = b.x - a.y; }
        C[t][jj] = z;
    }
    __syncthreads();
    {   // stage 1 (e^{+i})
        int k1 = t / 12, n2 = t % 12;
        float wr[16], wi[16];
        int m = n2*k1 % 192, step = (12*k1) % 192;
        #pragma unroll
        for (int n1 = 0; n1 < 16; n1++){
            wr[n1] = twc[m]; wi[n1] = tws[m];
            m += step; if (m >= 192) m -= 192;
        }
        #pragma unroll
        for (int jj = 0; jj < 8; jj++){
            float re = 0.f, im = 0.f;
            #pragma unroll
            for (int n1 = 0; n1 < 16; n1++){
                float2 v = C[12*n1 + n2][jj];
                re += v.x*wr[n1] - v.y*wi[n1];
                im += v.x*wi[n1] + v.y*wr[n1];
            }
            float2 a; a.x = re; a.y = im;
            A1[n2][k1][jj] = a;
        }
    }
    __syncthreads();
    {   // stage 2 (e^{+i}): Re->rowA, Im->rowB
        int k1 = t % 16, k2 = t / 16;
        float wr[12], wi[12];
        int m = 0, step = (16*k2) % 192;
        #pragma unroll
        for (int n2 = 0; n2 < 12; n2++){
            wr[n2] = twc[m]; wi[n2] = tws[m];
            m += step; if (m >= 192) m -= 192;
        }
        float* ob = out + (long)p*PIX + (long)r0*WW;
        #pragma unroll
        for (int jj = 0; jj < 8; jj++){
            float re = 0.f, im = 0.f;
            #pragma unroll
            for (int n2 = 0; n2 < 12; n2++){
                float2 a = A1[n2][k1][jj];
                re += a.x*wr[n2] - a.y*wi[n2];
                im += a.x*wi[n2] + a.y*wr[n2];
            }
            ob[(2*jj)*WW + t]   = re*INV_SQRT_N;
            ob[(2*jj+1)*WW + t] = im*INV_SQRT_N;
        }
    }
}

// ========== column FFT on [plane][kx][ky]: fully contiguous I/O ===========
template<int DIRSGN, bool RESCALE>
__global__ void k_cfft(const float* __restrict__ in, const float* __restrict__ tw,
                       const float* __restrict__ nrm, float* __restrict__ out){
    __shared__ float2 C[HH][9];
    __shared__ float2 A1[12][17][9];   // padded middle dim: bank fix
    __shared__ float twc[192], tws[192];
    const float sgn = (DIRSGN > 0) ? 1.f : -1.f;
    int p  = blockIdx.x / NG;
    int g  = blockIdx.x % NG;
    int j0 = g*8;
    int t  = threadIdx.x;
    twc[t] = tw[t]; tws[t] = tw[192+t];
    float scale = 1.f;
    if (RESCALE){
        int bt = p / NC;
        scale = sqrtf(nrm[bt]) / (sqrtf(nrm[64+bt]) + 1e-6f);
    }
    const float2* src = ((const float2*)in) + (long)p*FPIX;
    #pragma unroll
    for (int jj = 0; jj < 8; jj++){
        float2 v = {0.f, 0.f};
        if (j0 + jj < WF) v = src[(long)(j0+jj)*HH + t];
        v.x *= scale; v.y *= scale;
        C[t][jj] = v;
    }
    __syncthreads();
    {   // stage 1
        int k1 = t / 12, n2 = t % 12;
        float wr[16], wi[16];
        int m = n2*k1 % 192, step = (12*k1) % 192;
        #pragma unroll
        for (int n1 = 0; n1 < 16; n1++){
            wr[n1] = twc[m]; wi[n1] = sgn*tws[m];
            m += step; if (m >= 192) m -= 192;
        }
        #pragma unroll
        for (int jj = 0; jj < 8; jj++){
            float re = 0.f, im = 0.f;
            #pragma unroll
            for (int n1 = 0; n1 < 16; n1++){
                float2 v = C[12*n1 + n2][jj];
                re += v.x*wr[n1] - v.y*wi[n1];
                im += v.x*wi[n1] + v.y*wr[n1];
            }
            float2 a; a.x = re; a.y = im;
            A1[n2][k1][jj] = a;
        }
    }
    __syncthreads();
    {   // stage 2: ky == t
        int k1 = t % 16, k2 = t / 16;
        float wr[12], wi[12];
        int m = 0, step = (16*k2) % 192;
        #pragma unroll
        for (int n2 = 0; n2 < 12; n2++){
            wr[n2] = twc[m]; wi[n2] = sgn*tws[m];
            m += step; if (m >= 192) m -= 192;
        }
        float2* dst = ((float2*)out) + (long)p*FPIX;
        #pragma unroll
        for (int jj = 0; jj < 8; jj++){
            float re = 0.f, im = 0.f;
            #pragma unroll
            for (int n2 = 0; n2 < 12; n2++){
                float2 a = A1[n2][k1][jj];
                re += a.x*wr[n2] - a.y*wi[n2];
                im += a.x*wi[n2] + a.y*wr[n2];
            }
            if (j0 + jj < WF){
                float2 r; r.x = re*INV_SQRT_N; r.y = im*INV_SQRT_N;
                dst[(long)(j0+jj)*HH + t] = r;
            }
        }
    }
}

// ------- fused divergence projection (ch 0,1) + energy norm, in-place ------
__global__ void k_connorm(float* __restrict__ F, float* __restrict__ dst){
    int bt = blockIdx.y;
    __shared__ float red[256];
    float2* base = (float2*)(F + (long)bt*NC*FPIX*2);
    float s = 0.0f;
    for (int e = blockIdx.x*256 + threadIdx.x; e < 7*FPIX; e += gridDim.x*256){
        if (e < FPIX){
            int f = e;
            int kyi = f % HH, kxi = f / HH;
            float ky = (float)(kyi < 96 ? kyi : kyi - 192)/192.0f;
            float kx = (float)kxi/192.0f;
            float k2 = ky*ky + kx*kx;
            if (f == 0) k2 = 1.0f;
            float2 u = base[f], v = base[FPIX + f];
            float dr = (ky*u.x + kx*v.x)/k2;
            float di = (ky*u.y + kx*v.y)/k2;
            u.x -= ky*dr; u.y -= ky*di;
            v.x -= kx*dr; v.y -= kx*di;
            base[f] = u; base[FPIX + f] = v;
            s += u.x*u.x + u.y*u.y + v.x*v.x + v.y*v.y;
        } else {
            float2 w = base[(long)e + FPIX];   // channels 2..7
            s += w.x*w.x + w.y*w.y;
        }
    }
    red[threadIdx.x] = s; __syncthreads();
    for (int st = 128; st > 0; st >>= 1){
        if (threadIdx.x < st) red[threadIdx.x] += red[threadIdx.x + st];
        __syncthreads();
    }
    if (threadIdx.x == 0) atomicAdd(&dst[bt], red[0]);
}

// -------- scan h[t]=A*h[t-1]+X[t], with fused post-constrain on store ------
__global__ void k_scan(const float* __restrict__ Xf, const float* __restrict__ Abuf,
                       float* __restrict__ Hf){
    int idx = blockIdx.x*256 + threadIdx.x;
    int f = idx % FPIX; int tmp = idx / FPIX;
    int c = tmp % NC; int b = tmp / NC;
    if (c == 1) return;                   // handled by the c==0 thread
    if (c == 0){
        int kyi = f % HH, kxi = f / HH;
        float ky = (float)(kyi < 96 ? kyi : kyi - 192)/192.0f;
        float kx = (float)kxi/192.0f;
        float k2 = ky*ky + kx*kx;
        if (f == 0) k2 = 1.0f;
        long a0 = (((long)(b*NC + 0))*FPIX + f)*2;
        long a1 = (((long)(b*NC + 1))*FPIX + f)*2;
        float A0r = Abuf[a0], A0i = Abuf[a0+1];
        float A1r = Abuf[a1], A1i = Abuf[a1+1];
        float h0r = 0.f, h0i = 0.f, h1r = 0.f, h1i = 0.f;
        for (int t = 0; t < NT; t++){
            long e0 = (((((long)b*NT + t)*NC + 0)*FPIX) + f)*2;
            long e1 = (((((long)b*NT + t)*NC + 1)*FPIX) + f)*2;
            float x0r = Xf[e0], x0i = Xf[e0+1];
            float x1r = Xf[e1], x1i = Xf[e1+1];
            float n0r = A0r*h0r - A0i*h0i + x0r;
            float n0i = A0r*h0i + A0i*h0r + x0i;
            float n1r = A1r*h1r - A1i*h1i + x1r;
            float n1i = A1r*h1i + A1i*h1r + x1i;
            h0r = n0r; h0i = n0i; h1r = n1r; h1i = n1i;
            float dr = (ky*h0r + kx*h1r)/k2;
            float di = (ky*h0i + kx*h1i)/k2;
            Hf[e0]   = h0r - ky*dr;  Hf[e0+1] = h0i - ky*di;
            Hf[e1]   = h1r - kx*dr;  Hf[e1+1] = h1i - kx*di;
        }
    } else {
        long ao = (((long)(b*NC + c))*FPIX + f)*2;
        float ar = Abuf[ao], ai = Abuf[ao+1];
        float hr = 0.0f, hi = 0.0f;
        for (int t = 0; t < NT; t++){
            long e = (((((long)b*NT + t)*NC + c)*FPIX) + f)*2;
            float xr = Xf[e], xi = Xf[e+1];
            float nr = ar*hr - ai*hi + xr;
            float ni = ar*hi + ai*hr + xi;
            hr = nr; hi = ni;
            Hf[e] = hr; Hf[e+1] = hi;
        }
    }
}

// ---------------- per-(b,t) energy reduction ----------------
__global__ void k_norm(const float* __restrict__ F, float* __restrict__ dst){
    int bt = blockIdx.y;
    __shared__ float red[256];
    float s = 0.0f;
    const float* base = F + (long)bt*NC*FPIX*2;
    for (int e = blockIdx.x*256 + threadIdx.x; e < NC*FPIX; e += gridDim.x*256){
        float re = base[(long)e*2], im = base[(long)e*2 + 1];
        s += re*re + im*im;
    }
    red[threadIdx.x] = s; __syncthreads();
    for (int st = 128; st > 0; st >>= 1){
        if (threadIdx.x < st) red[threadIdx.x] += red[threadIdx.x + st];
        __syncthreads();
    }
    if (threadIdx.x == 0) atomicAdd(&dst[bt], red[0]);
}

extern "C" void kernel_launch(void* const* d_in, const int* in_sizes, int n_in,
                              void* d_out, int out_size, void* d_ws, size_t ws_size,
                              hipStream_t stream){
    const float* x   = (const float*)d_in[0];
    const float* dt  = (const float*)d_in[1];
    const float* w1  = (const float*)d_in[2];
    const float* b1  = (const float*)d_in[3];
    const float* w2  = (const float*)d_in[4];
    const float* b2  = (const float*)d_in[5];
    const float* c1w = (const float*)d_in[6];
    const float* c1b = (const float*)d_in[7];
    const float* c2w = (const float*)d_in[8];
    const float* c2b = (const float*)d_in[9];
    const float* c3w = (const float*)d_in[10];
    float* out = (float*)d_out;
    float* ws  = (float*)d_ws;

    const long RSZ = (long)NPLANE*FPIX*2;
    float* R1  = ws;
    float* R2  = ws + RSZ;
    float* AB  = R2 + RSZ;
    float* TW  = AB + (long)NB*NC*FPIX*2;
    float* NRM = TW + 384;

    unsigned short* ys1 = (unsigned short*)R2;
    unsigned short* dy1 = ys1 + (long)CHUNK*PIX*16;
    unsigned short* g2b = (unsigned short*)R1;
    unsigned short* g1b = (unsigned short*)R2;

    k_tab<<<2, 128, 0, stream>>>(TW, NRM);
    k_A<<<(FPIX + 255)/256, 256, 0, stream>>>(dt, w1, b1, w2, b2, AB);

    for (int ch = 0; ch < NIMG/CHUNK; ch++){
        int img0 = ch*CHUNK;
        int nb = CHUNK*144;
        k_conv1_m<<<nb, 256, 0, stream>>>(x, c1w, c1b, ys1, dy1, img0);
        k_conv2_m<<<nb, 256, 0, stream>>>(ys1, c2w, c2b, c3w, g2b);
        k_g1_m   <<<nb, 256, 0, stream>>>(g2b, dy1, c2w, g1b);
        k_xp_m   <<<nb, 256, 0, stream>>>(x, g1b, c1w, dt, out, img0);
    }

    k_rowfft2<<<NPLANE*12, 192, 0, stream>>>(out, TW, R1);
    k_cfft<-1,false><<<NPLANE*NG, 192, 0, stream>>>(R1, TW, NRM, R2);
    k_connorm<<<dim3(128, NIMG), 256, 0, stream>>>(R2, NRM);
    k_scan<<<NB*NC*FPIX/256, 256, 0, stream>>>(R2, AB, R1);
    k_norm<<<dim3(128, NIMG), 256, 0, stream>>>(R1, NRM + NIMG);
    k_cfft<+1,true><<<NPLANE*NG, 192, 0, stream>>>(R1, TW, NRM, R2);
    k_invrow2<<<NPLANE*12, 192, 0, stream>>>(R2, TW, out);
}